// Round 1
// baseline (3623.626 us; speedup 1.0000x reference)
//
#include <hip/hip_runtime.h>

#define DEVINL __device__ __forceinline__

static const int NPTS = 2048;

DEVINL unsigned fenc(float x) {
    int b = __float_as_int(x);
    return (b < 0) ? ~(unsigned)b : ((unsigned)b | 0x80000000u);
}
DEVINL float fdec(unsigned u) {
    return (u & 0x80000000u) ? __int_as_float((int)(u & 0x7fffffffu))
                             : __int_as_float((int)~u);
}

// ---------------------------------------------------------------------------
// KNN: one block handles R=8 rows (query points). Phase 1 computes
// score[r][m] = |x_m|^2 - 2 x_r . x_m  for all m into LDS (row features read
// as wave-uniform scalar loads). Phase 2: each wave owns R/4 rows, loads the
// 2048 scores into registers (32/lane) and does 20 iterations of wave argmin
// with tie-break by smaller index (matches stable argsort).
// ---------------------------------------------------------------------------
template<int C, int R>
__global__ __launch_bounds__(256) void knn_kernel(const float* __restrict__ X, int bs,
                                                  int* __restrict__ idxOut) {
    extern __shared__ float dist[];  // [R][NPTS]
    const int N = NPTS, K = 20;
    const int b = blockIdx.y;
    const int n0 = blockIdx.x * R;
    const float* __restrict__ Xb = X + (size_t)b * bs;
    const int tid = threadIdx.x;

    for (int j = 0; j < N / 256; ++j) {
        const int m = j * 256 + tid;
        float acc[R];
#pragma unroll
        for (int r = 0; r < R; ++r) acc[r] = 0.f;
        float sq = 0.f;
#pragma unroll 4
        for (int c = 0; c < C; ++c) {
            float v = Xb[c * N + m];
            sq += v * v;
#pragma unroll
            for (int r = 0; r < R; ++r) acc[r] += v * Xb[c * N + n0 + r];  // uniform -> s_load
        }
#pragma unroll
        for (int r = 0; r < R; ++r) {
            float d = sq - 2.f * acc[r];
            if (m == n0 + r) d = __builtin_inff();  // exclude self
            dist[r * N + m] = d;
        }
    }
    __syncthreads();

    const int w = tid >> 6, lane = tid & 63;
    const int RW = R / 4;
    for (int rr = 0; rr < RW; ++rr) {
        const int r = w * RW + rr;
        float v[32];
#pragma unroll
        for (int t = 0; t < 32; ++t) v[t] = dist[r * N + lane + 64 * t];
        unsigned sel = 0u;
        const int outBase = (b * N + n0 + r) * K;
        for (int it = 0; it < K; ++it) {
            float bd = __builtin_inff();
            int bi = 0x7fffffff;
#pragma unroll
            for (int t = 0; t < 32; ++t) {
                if (!((sel >> t) & 1u) && v[t] < bd) { bd = v[t]; bi = lane + 64 * t; }
            }
#pragma unroll
            for (int off = 32; off >= 1; off >>= 1) {
                float od = __shfl_down(bd, off);
                int oi = __shfl_down(bi, off);
                if (od < bd || (od == bd && oi < bi)) { bd = od; bi = oi; }
            }
            int winner = __shfl(bi, 0);
            if (lane == 0) idxOut[outBase + it] = winner;
            if (lane == (winner & 63)) sel |= (1u << (winner >> 6));
        }
    }
}

// ---------------------------------------------------------------------------
// U/T GEMMs: U[b][n][f] = sum_c W2[f][c] X[b][c][n]  (gather-friendly layout)
//            T[b][f][n] = sum_c (W1-W2)[f][c] X[b][c][n] + bias[f]
// 64n x 64f tile per block; 4n x 4f micro-tile per thread; W slices in LDS.
// ---------------------------------------------------------------------------
template<int F, int C>
__global__ __launch_bounds__(256) void ut_kernel(const float* __restrict__ X, int bs,
                                                 const float* __restrict__ W,
                                                 const float* __restrict__ bias,
                                                 float* __restrict__ U, float* __restrict__ T) {
    const int N = NPTS;
    __shared__ float Ws2[64][C + 1];
    __shared__ float Wsd[64][C + 1];
    const int n0 = blockIdx.x * 64, f0 = blockIdx.y * 64, b = blockIdx.z;
    const int tid = threadIdx.x;
    for (int i = tid; i < 64 * C; i += 256) {
        int ff = i / C, c = i - ff * C;
        float w1 = W[(f0 + ff) * (2 * C) + c];
        float w2 = W[(f0 + ff) * (2 * C) + C + c];
        Ws2[ff][c] = w2;
        Wsd[ff][c] = w1 - w2;
    }
    __syncthreads();
    const int nt = tid & 15, fg = tid >> 4;
    const float* __restrict__ Xb = X + (size_t)b * bs;
    float au[4][4], av[4][4];
#pragma unroll
    for (int i = 0; i < 4; ++i)
#pragma unroll
        for (int j = 0; j < 4; ++j) { au[i][j] = 0.f; av[i][j] = 0.f; }
#pragma unroll 4
    for (int c = 0; c < C; ++c) {
        const float4 xv = *(const float4*)&Xb[(size_t)c * N + n0 + nt * 4];
#pragma unroll
        for (int fi = 0; fi < 4; ++fi) {
            float w2v = Ws2[fg * 4 + fi][c];
            float wdv = Wsd[fg * 4 + fi][c];
            au[fi][0] += w2v * xv.x; au[fi][1] += w2v * xv.y;
            au[fi][2] += w2v * xv.z; au[fi][3] += w2v * xv.w;
            av[fi][0] += wdv * xv.x; av[fi][1] += wdv * xv.y;
            av[fi][2] += wdv * xv.z; av[fi][3] += wdv * xv.w;
        }
    }
#pragma unroll
    for (int ni = 0; ni < 4; ++ni) {
        int n = n0 + nt * 4 + ni;
        float4 uv = make_float4(au[0][ni], au[1][ni], au[2][ni], au[3][ni]);
        *(float4*)&U[((size_t)b * N + n) * F + f0 + fg * 4] = uv;
    }
#pragma unroll
    for (int fi = 0; fi < 4; ++fi) {
        int f = f0 + fg * 4 + fi;
        float bv = bias[f];
        float4 tv = make_float4(av[fi][0] + bv, av[fi][1] + bv, av[fi][2] + bv, av[fi][3] + bv);
        *(float4*)&T[((size_t)b * F + f) * N + n0 + nt * 4] = tv;
    }
}

// ---------------------------------------------------------------------------
// Gather-max: y[b][f][n] = T[b][f][n] + max_{j<20} U[b][idx[n][j]][f]
// One thread per point; neighbor indices staged in LDS then registers.
// Writes directly into the H concat buffer slice (bsY = 320*N).
// ---------------------------------------------------------------------------
template<int F>
__global__ __launch_bounds__(256) void gathermax_kernel(const float* __restrict__ U,
                                                        const float* __restrict__ T,
                                                        const int* __restrict__ idx,
                                                        float* __restrict__ Y, int bsY) {
    const int N = NPTS, K = 20;
    __shared__ int sidx[256 * 20];
    const int b = blockIdx.y, n0 = blockIdx.x * 256, tid = threadIdx.x;
    for (int t = tid; t < 256 * K; t += 256) sidx[t] = idx[(b * N + n0) * K + t];
    __syncthreads();
    int rows[20];
#pragma unroll
    for (int j = 0; j < K; ++j) rows[j] = sidx[tid * K + j];
    const int n = n0 + tid;
    const float* __restrict__ Ub = U + (size_t)b * N * F;
#pragma unroll 1
    for (int fc = 0; fc < F; fc += 8) {
        float mx[8];
#pragma unroll
        for (int i = 0; i < 8; ++i) mx[i] = -__builtin_inff();
#pragma unroll 4
        for (int j = 0; j < K; ++j) {
            const float4* up = (const float4*)&Ub[(size_t)rows[j] * F + fc];
            float4 a = up[0], c2 = up[1];
            mx[0] = fmaxf(mx[0], a.x);  mx[1] = fmaxf(mx[1], a.y);
            mx[2] = fmaxf(mx[2], a.z);  mx[3] = fmaxf(mx[3], a.w);
            mx[4] = fmaxf(mx[4], c2.x); mx[5] = fmaxf(mx[5], c2.y);
            mx[6] = fmaxf(mx[6], c2.z); mx[7] = fmaxf(mx[7], c2.w);
        }
#pragma unroll
        for (int i = 0; i < 8; ++i) {
            float tv = T[((size_t)b * F + fc + i) * N + n];
            Y[(size_t)b * bsY + (size_t)(fc + i) * N + n] = tv + mx[i];
        }
    }
}

// ---------------------------------------------------------------------------
// conv0 fused with global max over n: M[b][f] = max_n sum_c W[f][c] H[b][c][n]
// (affine+relu applied later in fc kernel; monotone since s>0).
// 64f x 128n tile per block; K chunks of 32 staged in LDS; encoded atomicMax.
// ---------------------------------------------------------------------------
__global__ __launch_bounds__(256) void conv0max_kernel(const float* __restrict__ Hbuf,
                                                       const float* __restrict__ W,
                                                       unsigned* __restrict__ M) {
    const int N = NPTS;
    __shared__ float Hs[32][128];
    __shared__ float Ws[64][33];
    const int n0 = blockIdx.x * 128, f0 = blockIdx.y * 64, b = blockIdx.z;
    const int tid = threadIdx.x, nt = tid & 15, fg = tid >> 4;
    float acc[4][8];
#pragma unroll
    for (int i = 0; i < 4; ++i)
#pragma unroll
        for (int j = 0; j < 8; ++j) acc[i][j] = 0.f;

    for (int c0 = 0; c0 < 320; c0 += 32) {
        for (int t = tid; t < 32 * 128; t += 256) {
            int ci = t >> 7, nn = t & 127;
            Hs[ci][nn] = Hbuf[((size_t)b * 320 + c0 + ci) * N + n0 + nn];
        }
        for (int t = tid; t < 64 * 32; t += 256) {
            int ff = t >> 5, cc = t & 31;
            Ws[ff][cc] = W[(f0 + ff) * 320 + c0 + cc];
        }
        __syncthreads();
#pragma unroll 8
        for (int ci = 0; ci < 32; ++ci) {
            float4 ha = *(const float4*)&Hs[ci][nt * 4];
            float4 hb = *(const float4*)&Hs[ci][64 + nt * 4];
#pragma unroll
            for (int fi = 0; fi < 4; ++fi) {
                float wv = Ws[fg * 4 + fi][ci];
                acc[fi][0] += wv * ha.x; acc[fi][1] += wv * ha.y;
                acc[fi][2] += wv * ha.z; acc[fi][3] += wv * ha.w;
                acc[fi][4] += wv * hb.x; acc[fi][5] += wv * hb.y;
                acc[fi][6] += wv * hb.z; acc[fi][7] += wv * hb.w;
            }
        }
        __syncthreads();
    }
#pragma unroll
    for (int fi = 0; fi < 4; ++fi) {
        float m = acc[fi][0];
#pragma unroll
        for (int j = 1; j < 8; ++j) m = fmaxf(m, acc[fi][j]);
        for (int off = 8; off >= 1; off >>= 1) m = fmaxf(m, __shfl_down(m, off, 16));
        if (nt == 0) atomicMax(&M[(b << 10) + f0 + fg * 4 + fi], fenc(m));
    }
}

// ---------------------------------------------------------------------------
// Fused head: decode max -> conv0 affine+relu -> fc0 -> fc1 -> fc2.
// One block per batch element.
// ---------------------------------------------------------------------------
__global__ __launch_bounds__(256) void fc_kernel(const unsigned* __restrict__ M,
    const float* __restrict__ cb, const float* __restrict__ cs, const float* __restrict__ ct,
    const float* __restrict__ w0, const float* __restrict__ b0, const float* __restrict__ s0, const float* __restrict__ t0,
    const float* __restrict__ w1, const float* __restrict__ b1, const float* __restrict__ s1, const float* __restrict__ t1,
    const float* __restrict__ w2, const float* __restrict__ b2, const float* __restrict__ s2, const float* __restrict__ t2,
    float* __restrict__ out) {
    __shared__ float g0[1024], g1[512], g2[256];
    const int b = blockIdx.x, tid = threadIdx.x;
    for (int f = tid; f < 1024; f += 256) {
        float z = fdec(M[b * 1024 + f]);
        float g = cs[f] * (z + cb[f]) + ct[f];
        g0[f] = fmaxf(g, 0.f);
    }
    __syncthreads();
    for (int f = tid; f < 512; f += 256) {
        const float4* wp = (const float4*)(w0 + (size_t)f * 1024);
        float acc = 0.f;
#pragma unroll 4
        for (int c = 0; c < 256; ++c) {
            float4 wv = wp[c];
            float4 gv = *(const float4*)&g0[c * 4];
            acc += wv.x * gv.x + wv.y * gv.y + wv.z * gv.z + wv.w * gv.w;
        }
        float g = s0[f] * (acc + b0[f]) + t0[f];
        g1[f] = fmaxf(g, 0.f);
    }
    __syncthreads();
    if (tid < 256) {
        const float4* wp = (const float4*)(w1 + (size_t)tid * 512);
        float acc = 0.f;
#pragma unroll 4
        for (int c = 0; c < 128; ++c) {
            float4 wv = wp[c];
            float4 gv = *(const float4*)&g1[c * 4];
            acc += wv.x * gv.x + wv.y * gv.y + wv.z * gv.z + wv.w * gv.w;
        }
        float g = s1[tid] * (acc + b1[tid]) + t1[tid];
        g2[tid] = fmaxf(g, 0.f);
    }
    __syncthreads();
    if (tid < 40) {
        const float4* wp = (const float4*)(w2 + (size_t)tid * 256);
        float acc = 0.f;
#pragma unroll 4
        for (int c = 0; c < 64; ++c) {
            float4 wv = wp[c];
            float4 gv = *(const float4*)&g2[c * 4];
            acc += wv.x * gv.x + wv.y * gv.y + wv.z * gv.z + wv.w * gv.w;
        }
        float g = s2[tid] * (acc + b2[tid]) + t2[tid];
        out[b * 40 + tid] = fmaxf(g, 0.f);
    }
}

// ---------------------------------------------------------------------------
extern "C" void kernel_launch(void* const* d_in, const int* in_sizes, int n_in,
                              void* d_out, int out_size, void* d_ws, size_t ws_size,
                              hipStream_t stream) {
    const float* x       = (const float*)d_in[0];
    const float* ec0_w   = (const float*)d_in[1];
    const float* ec0_b   = (const float*)d_in[2];
    const float* ec1_w   = (const float*)d_in[3];
    const float* ec1_b   = (const float*)d_in[4];
    const float* ec2_w   = (const float*)d_in[5];
    const float* ec2_b   = (const float*)d_in[6];
    const float* ec3_w   = (const float*)d_in[7];
    const float* ec3_b   = (const float*)d_in[8];
    const float* conv0_w = (const float*)d_in[9];
    const float* conv0_b = (const float*)d_in[10];
    const float* conv0_s = (const float*)d_in[11];
    const float* conv0_t = (const float*)d_in[12];
    const float* fc0_w   = (const float*)d_in[13];
    const float* fc0_b   = (const float*)d_in[14];
    const float* fc0_s   = (const float*)d_in[15];
    const float* fc0_t   = (const float*)d_in[16];
    const float* fc1_w   = (const float*)d_in[17];
    const float* fc1_b   = (const float*)d_in[18];
    const float* fc1_s   = (const float*)d_in[19];
    const float* fc1_t   = (const float*)d_in[20];
    const float* fc2_w   = (const float*)d_in[21];
    const float* fc2_b   = (const float*)d_in[22];
    const float* fc2_s   = (const float*)d_in[23];
    const float* fc2_t   = (const float*)d_in[24];
    float* out = (float*)d_out;

    char* ws = (char*)d_ws;
    const int B = 16, N = NPTS;
    // ws layout (bytes):
    float* Hc   = (float*)(ws + 0);         // [16][320][2048]  41,943,040 B
    float* U    = (float*)(ws + 41943040);  // [16][2048][128]  16,777,216 B
    float* T    = (float*)(ws + 58720256);  // [16][128][2048]  16,777,216 B
    int*   I    = (int*)  (ws + 75497472);  // [16][2048][20]    2,621,440 B
    unsigned* M = (unsigned*)(ws + 78118912); // [16][1024]         65,536 B

    (void)hipFuncSetAttribute((const void*)knn_kernel<3, 8>,
                              hipFuncAttributeMaxDynamicSharedMemorySize, 8 * N * 4);
    (void)hipFuncSetAttribute((const void*)knn_kernel<64, 8>,
                              hipFuncAttributeMaxDynamicSharedMemorySize, 8 * N * 4);

    dim3 blk(256);
    const int bsX0 = 3 * N, bsH = 320 * N;

    // ---- Layer 0 (C=3 -> F=64), output -> H[:, 0:64) ----
    knn_kernel<3, 8><<<dim3(N / 8, B), blk, 8 * N * 4, stream>>>(x, bsX0, I);
    ut_kernel<64, 3><<<dim3(N / 64, 1, B), blk, 0, stream>>>(x, bsX0, ec0_w, ec0_b, U, T);
    gathermax_kernel<64><<<dim3(N / 256, B), blk, 0, stream>>>(U, T, I, Hc, bsH);

    // ---- Layer 1 (C=64 -> F=64), input H[:,0:64), output -> H[:, 64:128) ----
    knn_kernel<64, 8><<<dim3(N / 8, B), blk, 8 * N * 4, stream>>>(Hc, bsH, I);
    ut_kernel<64, 64><<<dim3(N / 64, 1, B), blk, 0, stream>>>(Hc, bsH, ec1_w, ec1_b, U, T);
    gathermax_kernel<64><<<dim3(N / 256, B), blk, 0, stream>>>(U, T, I, Hc + (size_t)64 * N, bsH);

    // ---- Layer 2 (C=64 -> F=64), input H[:,64:128), output -> H[:, 128:192) ----
    knn_kernel<64, 8><<<dim3(N / 8, B), blk, 8 * N * 4, stream>>>(Hc + (size_t)64 * N, bsH, I);
    ut_kernel<64, 64><<<dim3(N / 64, 1, B), blk, 0, stream>>>(Hc + (size_t)64 * N, bsH, ec2_w, ec2_b, U, T);
    gathermax_kernel<64><<<dim3(N / 256, B), blk, 0, stream>>>(U, T, I, Hc + (size_t)128 * N, bsH);

    // ---- Layer 3 (C=64 -> F=128), input H[:,128:192), output -> H[:, 192:320) ----
    knn_kernel<64, 8><<<dim3(N / 8, B), blk, 8 * N * 4, stream>>>(Hc + (size_t)128 * N, bsH, I);
    ut_kernel<128, 64><<<dim3(N / 64, 2, B), blk, 0, stream>>>(Hc + (size_t)128 * N, bsH, ec3_w, ec3_b, U, T);
    gathermax_kernel<128><<<dim3(N / 256, B), blk, 0, stream>>>(U, T, I, Hc + (size_t)192 * N, bsH);

    // ---- conv0 + global max (fused) ----
    (void)hipMemsetAsync(M, 0, B * 1024 * sizeof(unsigned), stream);
    conv0max_kernel<<<dim3(N / 128, 1024 / 64, B), blk, 0, stream>>>(Hc, conv0_w, M);

    // ---- head ----
    fc_kernel<<<dim3(B), blk, 0, stream>>>(M, conv0_b, conv0_s, conv0_t,
                                           fc0_w, fc0_b, fc0_s, fc0_t,
                                           fc1_w, fc1_b, fc1_s, fc1_t,
                                           fc2_w, fc2_b, fc2_s, fc2_t, out);
}

// Round 2
// 2566.762 us; speedup vs baseline: 1.4118x; 1.4118x over previous
//
#include <hip/hip_runtime.h>

#define DEVINL __device__ __forceinline__

static const int NPTS = 2048;

DEVINL unsigned fenc(float x) {
    int b = __float_as_int(x);
    return (b < 0) ? ~(unsigned)b : ((unsigned)b | 0x80000000u);
}
DEVINL float fdec(unsigned u) {
    return (u & 0x80000000u) ? __int_as_float((int)(u & 0x7fffffffu))
                             : __int_as_float((int)~u);
}
DEVINL unsigned long long u64min(unsigned long long a, unsigned long long b) {
    return (b < a) ? b : a;
}

// ---------------------------------------------------------------------------
// sq: sq[b][m] = sum_c X[b][c][m]^2.  sqOut has batch stride sqStride.
// ---------------------------------------------------------------------------
template<int C>
__global__ __launch_bounds__(256) void sq_kernel(const float* __restrict__ X, int bs,
                                                 float* __restrict__ sqOut, int sqStride) {
    const int b = blockIdx.y;
    const int m = blockIdx.x * 256 + threadIdx.x;
    const float* __restrict__ Xb = X + (size_t)b * bs;
    float s = 0.f;
#pragma unroll 8
    for (int c = 0; c < C; ++c) { float v = Xb[(size_t)c * NPTS + m]; s += v * v; }
    sqOut[(size_t)b * sqStride + m] = s;
}

// ---------------------------------------------------------------------------
// dist GEMM: D[bb][n][m] = sq[m] - 2 * sum_c X[c][n] X[c][m] for 2 batches.
// 64x64 tile, 4x4 micro-tile, A/B panels in LDS (stride 68 keeps b128 align).
// ---------------------------------------------------------------------------
template<int C>
__global__ __launch_bounds__(256) void distgemm_kernel(const float* __restrict__ X, int bs, int b0,
                                                       const float* __restrict__ sqB, int sqStride,
                                                       float* __restrict__ D) {
    const int N = NPTS;
    __shared__ float As[C][68];
    __shared__ float Bs[C][68];
    const int bb = blockIdx.z, b = b0 + bb;
    const int n0 = blockIdx.y * 64, m0 = blockIdx.x * 64;
    const float* __restrict__ Xb = X + (size_t)b * bs;
    const int tid = threadIdx.x;
    for (int i = tid; i < C * 64; i += 256) {
        int c = i >> 6, col = i & 63;
        As[c][col] = Xb[(size_t)c * N + n0 + col];
        Bs[c][col] = Xb[(size_t)c * N + m0 + col];
    }
    __syncthreads();
    const int nt = tid >> 4, mt = tid & 15;
    float acc[4][4];
#pragma unroll
    for (int i = 0; i < 4; ++i)
#pragma unroll
        for (int j = 0; j < 4; ++j) acc[i][j] = 0.f;
#pragma unroll 8
    for (int c = 0; c < C; ++c) {
        float4 a = *(const float4*)&As[c][nt * 4];
        float4 v = *(const float4*)&Bs[c][mt * 4];
        acc[0][0] += a.x * v.x; acc[0][1] += a.x * v.y; acc[0][2] += a.x * v.z; acc[0][3] += a.x * v.w;
        acc[1][0] += a.y * v.x; acc[1][1] += a.y * v.y; acc[1][2] += a.y * v.z; acc[1][3] += a.y * v.w;
        acc[2][0] += a.z * v.x; acc[2][1] += a.z * v.y; acc[2][2] += a.z * v.z; acc[2][3] += a.z * v.w;
        acc[3][0] += a.w * v.x; acc[3][1] += a.w * v.y; acc[3][2] += a.w * v.z; acc[3][3] += a.w * v.w;
    }
    const float* __restrict__ sqp = sqB + (size_t)b * sqStride;
    const float4 sv = *(const float4*)&sqp[m0 + mt * 4];
#pragma unroll
    for (int i = 0; i < 4; ++i) {
        int row = n0 + nt * 4 + i;
        float4 o = make_float4(sv.x - 2.f * acc[i][0], sv.y - 2.f * acc[i][1],
                               sv.z - 2.f * acc[i][2], sv.w - 2.f * acc[i][3]);
        *(float4*)&D[((size_t)bb * N + row) * N + m0 + mt * 4] = o;
    }
}

// ---------------------------------------------------------------------------
// select: one wave per row. Row's 2048 scores -> u64 keys (fenc(d)<<32|idx) in
// 32 regs/lane. 20x: filter(key>last) -> 5-level tree min -> 6-step shfl min.
// Keys unique => exact argsort tie-break (smaller idx wins) for free.
// ---------------------------------------------------------------------------
__global__ __launch_bounds__(256) void select_kernel(const float* __restrict__ D, int b0,
                                                     int* __restrict__ Iout) {
    const int N = NPTS, K = 20;
    const int w = threadIdx.x >> 6, lane = threadIdx.x & 63;
    const int rowg = blockIdx.x * 4 + w;
    const int bb = rowg >> 11, n = rowg & 2047, b = b0 + bb;
    const float* __restrict__ rp = D + ((size_t)bb * N + n) * N;
    unsigned long long vk[32];
#pragma unroll
    for (int q = 0; q < 8; ++q) {
        const float4 v = *(const float4*)&rp[lane * 4 + q * 256];
        const int base = lane * 4 + q * 256;
        float vv[4] = {v.x, v.y, v.z, v.w};
#pragma unroll
        for (int j = 0; j < 4; ++j) {
            unsigned long long key = ((unsigned long long)fenc(vv[j]) << 32) | (unsigned)(base + j);
            if (base + j == n) key = ~0ull;
            vk[q * 4 + j] = key;
        }
    }
    const int outBase = (b * N + n) * K;
    unsigned long long last = 0ull;
    for (int it = 0; it < K; ++it) {
        unsigned long long t16[16];
#pragma unroll
        for (int i = 0; i < 16; ++i) {
            unsigned long long a = (vk[i] > last) ? vk[i] : ~0ull;
            unsigned long long c = (vk[i + 16] > last) ? vk[i + 16] : ~0ull;
            t16[i] = u64min(a, c);
        }
        unsigned long long t8[8];
#pragma unroll
        for (int i = 0; i < 8; ++i) t8[i] = u64min(t16[i], t16[i + 8]);
        unsigned long long t4[4];
#pragma unroll
        for (int i = 0; i < 4; ++i) t4[i] = u64min(t8[i], t8[i + 4]);
        unsigned long long best = u64min(u64min(t4[0], t4[2]), u64min(t4[1], t4[3]));
#pragma unroll
        for (int off = 32; off >= 1; off >>= 1) {
            unsigned long long o = __shfl_down(best, off);
            best = u64min(best, o);
        }
        best = __shfl(best, 0);
        if (lane == 0) Iout[outBase + it] = (int)(unsigned)(best & 0xffffffffu);
        last = best;
    }
}

// ---------------------------------------------------------------------------
// select0: layer-0 fused (C=3) — computes scores inline, no D buffer.
// Same arithmetic as baseline: d = (xm^2+ym^2+zm^2) - 2*(xr*xm+yr*ym+zr*zm).
// ---------------------------------------------------------------------------
__global__ __launch_bounds__(256) void select0_kernel(const float* __restrict__ X,
                                                      int* __restrict__ Iout) {
    const int N = NPTS, K = 20;
    const int w = threadIdx.x >> 6, lane = threadIdx.x & 63;
    const int rowg = blockIdx.x * 4 + w;
    const int b = rowg >> 11, n = rowg & 2047;
    const float* __restrict__ Xb = X + (size_t)b * 3 * N;
    const float xr = Xb[n], yr = Xb[N + n], zr = Xb[2 * N + n];
    unsigned long long vk[32];
#pragma unroll
    for (int q = 0; q < 8; ++q) {
        const int base = lane * 4 + q * 256;
        const float4 xm = *(const float4*)&Xb[base];
        const float4 ym = *(const float4*)&Xb[N + base];
        const float4 zm = *(const float4*)&Xb[2 * N + base];
        float mx[4] = {xm.x, xm.y, xm.z, xm.w};
        float my[4] = {ym.x, ym.y, ym.z, ym.w};
        float mz[4] = {zm.x, zm.y, zm.z, zm.w};
#pragma unroll
        for (int j = 0; j < 4; ++j) {
            float sq = mx[j] * mx[j] + my[j] * my[j] + mz[j] * mz[j];
            float dot = xr * mx[j] + yr * my[j] + zr * mz[j];
            float d = sq - 2.f * dot;
            unsigned long long key = ((unsigned long long)fenc(d) << 32) | (unsigned)(base + j);
            if (base + j == n) key = ~0ull;
            vk[q * 4 + j] = key;
        }
    }
    const int outBase = (b * N + n) * K;
    unsigned long long last = 0ull;
    for (int it = 0; it < K; ++it) {
        unsigned long long t16[16];
#pragma unroll
        for (int i = 0; i < 16; ++i) {
            unsigned long long a = (vk[i] > last) ? vk[i] : ~0ull;
            unsigned long long c = (vk[i + 16] > last) ? vk[i + 16] : ~0ull;
            t16[i] = u64min(a, c);
        }
        unsigned long long t8[8];
#pragma unroll
        for (int i = 0; i < 8; ++i) t8[i] = u64min(t16[i], t16[i + 8]);
        unsigned long long t4[4];
#pragma unroll
        for (int i = 0; i < 4; ++i) t4[i] = u64min(t8[i], t8[i + 4]);
        unsigned long long best = u64min(u64min(t4[0], t4[2]), u64min(t4[1], t4[3]));
#pragma unroll
        for (int off = 32; off >= 1; off >>= 1) {
            unsigned long long o = __shfl_down(best, off);
            best = u64min(best, o);
        }
        best = __shfl(best, 0);
        if (lane == 0) Iout[outBase + it] = (int)(unsigned)(best & 0xffffffffu);
        last = best;
    }
}

// ---------------------------------------------------------------------------
// U/T GEMMs (unchanged from round 1).
// ---------------------------------------------------------------------------
template<int F, int C>
__global__ __launch_bounds__(256) void ut_kernel(const float* __restrict__ X, int bs,
                                                 const float* __restrict__ W,
                                                 const float* __restrict__ bias,
                                                 float* __restrict__ U, float* __restrict__ T) {
    const int N = NPTS;
    __shared__ float Ws2[64][C + 1];
    __shared__ float Wsd[64][C + 1];
    const int n0 = blockIdx.x * 64, f0 = blockIdx.y * 64, b = blockIdx.z;
    const int tid = threadIdx.x;
    for (int i = tid; i < 64 * C; i += 256) {
        int ff = i / C, c = i - ff * C;
        float w1 = W[(f0 + ff) * (2 * C) + c];
        float w2 = W[(f0 + ff) * (2 * C) + C + c];
        Ws2[ff][c] = w2;
        Wsd[ff][c] = w1 - w2;
    }
    __syncthreads();
    const int nt = tid & 15, fg = tid >> 4;
    const float* __restrict__ Xb = X + (size_t)b * bs;
    float au[4][4], av[4][4];
#pragma unroll
    for (int i = 0; i < 4; ++i)
#pragma unroll
        for (int j = 0; j < 4; ++j) { au[i][j] = 0.f; av[i][j] = 0.f; }
#pragma unroll 4
    for (int c = 0; c < C; ++c) {
        const float4 xv = *(const float4*)&Xb[(size_t)c * N + n0 + nt * 4];
#pragma unroll
        for (int fi = 0; fi < 4; ++fi) {
            float w2v = Ws2[fg * 4 + fi][c];
            float wdv = Wsd[fg * 4 + fi][c];
            au[fi][0] += w2v * xv.x; au[fi][1] += w2v * xv.y;
            au[fi][2] += w2v * xv.z; au[fi][3] += w2v * xv.w;
            av[fi][0] += wdv * xv.x; av[fi][1] += wdv * xv.y;
            av[fi][2] += wdv * xv.z; av[fi][3] += wdv * xv.w;
        }
    }
#pragma unroll
    for (int ni = 0; ni < 4; ++ni) {
        int n = n0 + nt * 4 + ni;
        float4 uv = make_float4(au[0][ni], au[1][ni], au[2][ni], au[3][ni]);
        *(float4*)&U[((size_t)b * N + n) * F + f0 + fg * 4] = uv;
    }
#pragma unroll
    for (int fi = 0; fi < 4; ++fi) {
        int f = f0 + fg * 4 + fi;
        float bv = bias[f];
        float4 tv = make_float4(av[fi][0] + bv, av[fi][1] + bv, av[fi][2] + bv, av[fi][3] + bv);
        *(float4*)&T[((size_t)b * F + f) * N + n0 + nt * 4] = tv;
    }
}

// ---------------------------------------------------------------------------
// Gather-max (unchanged from round 1).
// ---------------------------------------------------------------------------
template<int F>
__global__ __launch_bounds__(256) void gathermax_kernel(const float* __restrict__ U,
                                                        const float* __restrict__ T,
                                                        const int* __restrict__ idx,
                                                        float* __restrict__ Y, int bsY) {
    const int N = NPTS, K = 20;
    __shared__ int sidx[256 * 20];
    const int b = blockIdx.y, n0 = blockIdx.x * 256, tid = threadIdx.x;
    for (int t = tid; t < 256 * K; t += 256) sidx[t] = idx[(b * N + n0) * K + t];
    __syncthreads();
    int rows[20];
#pragma unroll
    for (int j = 0; j < K; ++j) rows[j] = sidx[tid * K + j];
    const int n = n0 + tid;
    const float* __restrict__ Ub = U + (size_t)b * N * F;
#pragma unroll 1
    for (int fc = 0; fc < F; fc += 8) {
        float mx[8];
#pragma unroll
        for (int i = 0; i < 8; ++i) mx[i] = -__builtin_inff();
#pragma unroll 4
        for (int j = 0; j < K; ++j) {
            const float4* up = (const float4*)&Ub[(size_t)rows[j] * F + fc];
            float4 a = up[0], c2 = up[1];
            mx[0] = fmaxf(mx[0], a.x);  mx[1] = fmaxf(mx[1], a.y);
            mx[2] = fmaxf(mx[2], a.z);  mx[3] = fmaxf(mx[3], a.w);
            mx[4] = fmaxf(mx[4], c2.x); mx[5] = fmaxf(mx[5], c2.y);
            mx[6] = fmaxf(mx[6], c2.z); mx[7] = fmaxf(mx[7], c2.w);
        }
#pragma unroll
        for (int i = 0; i < 8; ++i) {
            float tv = T[((size_t)b * F + fc + i) * N + n];
            Y[(size_t)b * bsY + (size_t)(fc + i) * N + n] = tv + mx[i];
        }
    }
}

// ---------------------------------------------------------------------------
// conv0 + global max (unchanged from round 1).
// ---------------------------------------------------------------------------
__global__ __launch_bounds__(256) void conv0max_kernel(const float* __restrict__ Hbuf,
                                                       const float* __restrict__ W,
                                                       unsigned* __restrict__ M) {
    const int N = NPTS;
    __shared__ float Hs[32][128];
    __shared__ float Ws[64][33];
    const int n0 = blockIdx.x * 128, f0 = blockIdx.y * 64, b = blockIdx.z;
    const int tid = threadIdx.x, nt = tid & 15, fg = tid >> 4;
    float acc[4][8];
#pragma unroll
    for (int i = 0; i < 4; ++i)
#pragma unroll
        for (int j = 0; j < 8; ++j) acc[i][j] = 0.f;

    for (int c0 = 0; c0 < 320; c0 += 32) {
        for (int t = tid; t < 32 * 128; t += 256) {
            int ci = t >> 7, nn = t & 127;
            Hs[ci][nn] = Hbuf[((size_t)b * 320 + c0 + ci) * N + n0 + nn];
        }
        for (int t = tid; t < 64 * 32; t += 256) {
            int ff = t >> 5, cc = t & 31;
            Ws[ff][cc] = W[(f0 + ff) * 320 + c0 + cc];
        }
        __syncthreads();
#pragma unroll 8
        for (int ci = 0; ci < 32; ++ci) {
            float4 ha = *(const float4*)&Hs[ci][nt * 4];
            float4 hb = *(const float4*)&Hs[ci][64 + nt * 4];
#pragma unroll
            for (int fi = 0; fi < 4; ++fi) {
                float wv = Ws[fg * 4 + fi][ci];
                acc[fi][0] += wv * ha.x; acc[fi][1] += wv * ha.y;
                acc[fi][2] += wv * ha.z; acc[fi][3] += wv * ha.w;
                acc[fi][4] += wv * hb.x; acc[fi][5] += wv * hb.y;
                acc[fi][6] += wv * hb.z; acc[fi][7] += wv * hb.w;
            }
        }
        __syncthreads();
    }
#pragma unroll
    for (int fi = 0; fi < 4; ++fi) {
        float m = acc[fi][0];
#pragma unroll
        for (int j = 1; j < 8; ++j) m = fmaxf(m, acc[fi][j]);
        for (int off = 8; off >= 1; off >>= 1) m = fmaxf(m, __shfl_down(m, off, 16));
        if (nt == 0) atomicMax(&M[(b << 10) + f0 + fg * 4 + fi], fenc(m));
    }
}

// ---------------------------------------------------------------------------
// Fused head (unchanged from round 1).
// ---------------------------------------------------------------------------
__global__ __launch_bounds__(256) void fc_kernel(const unsigned* __restrict__ M,
    const float* __restrict__ cb, const float* __restrict__ cs, const float* __restrict__ ct,
    const float* __restrict__ w0, const float* __restrict__ b0, const float* __restrict__ s0, const float* __restrict__ t0,
    const float* __restrict__ w1, const float* __restrict__ b1, const float* __restrict__ s1, const float* __restrict__ t1,
    const float* __restrict__ w2, const float* __restrict__ b2, const float* __restrict__ s2, const float* __restrict__ t2,
    float* __restrict__ out) {
    __shared__ float g0[1024], g1[512], g2[256];
    const int b = blockIdx.x, tid = threadIdx.x;
    for (int f = tid; f < 1024; f += 256) {
        float z = fdec(M[b * 1024 + f]);
        float g = cs[f] * (z + cb[f]) + ct[f];
        g0[f] = fmaxf(g, 0.f);
    }
    __syncthreads();
    for (int f = tid; f < 512; f += 256) {
        const float4* wp = (const float4*)(w0 + (size_t)f * 1024);
        float acc = 0.f;
#pragma unroll 4
        for (int c = 0; c < 256; ++c) {
            float4 wv = wp[c];
            float4 gv = *(const float4*)&g0[c * 4];
            acc += wv.x * gv.x + wv.y * gv.y + wv.z * gv.z + wv.w * gv.w;
        }
        float g = s0[f] * (acc + b0[f]) + t0[f];
        g1[f] = fmaxf(g, 0.f);
    }
    __syncthreads();
    if (tid < 256) {
        const float4* wp = (const float4*)(w1 + (size_t)tid * 512);
        float acc = 0.f;
#pragma unroll 4
        for (int c = 0; c < 128; ++c) {
            float4 wv = wp[c];
            float4 gv = *(const float4*)&g1[c * 4];
            acc += wv.x * gv.x + wv.y * gv.y + wv.z * gv.z + wv.w * gv.w;
        }
        float g = s1[tid] * (acc + b1[tid]) + t1[tid];
        g2[tid] = fmaxf(g, 0.f);
    }
    __syncthreads();
    if (tid < 40) {
        const float4* wp = (const float4*)(w2 + (size_t)tid * 256);
        float acc = 0.f;
#pragma unroll 4
        for (int c = 0; c < 64; ++c) {
            float4 wv = wp[c];
            float4 gv = *(const float4*)&g2[c * 4];
            acc += wv.x * gv.x + wv.y * gv.y + wv.z * gv.z + wv.w * gv.w;
        }
        float g = s2[tid] * (acc + b2[tid]) + t2[tid];
        out[b * 40 + tid] = fmaxf(g, 0.f);
    }
}

// ---------------------------------------------------------------------------
extern "C" void kernel_launch(void* const* d_in, const int* in_sizes, int n_in,
                              void* d_out, int out_size, void* d_ws, size_t ws_size,
                              hipStream_t stream) {
    const float* x       = (const float*)d_in[0];
    const float* ec0_w   = (const float*)d_in[1];
    const float* ec0_b   = (const float*)d_in[2];
    const float* ec1_w   = (const float*)d_in[3];
    const float* ec1_b   = (const float*)d_in[4];
    const float* ec2_w   = (const float*)d_in[5];
    const float* ec2_b   = (const float*)d_in[6];
    const float* ec3_w   = (const float*)d_in[7];
    const float* ec3_b   = (const float*)d_in[8];
    const float* conv0_w = (const float*)d_in[9];
    const float* conv0_b = (const float*)d_in[10];
    const float* conv0_s = (const float*)d_in[11];
    const float* conv0_t = (const float*)d_in[12];
    const float* fc0_w   = (const float*)d_in[13];
    const float* fc0_b   = (const float*)d_in[14];
    const float* fc0_s   = (const float*)d_in[15];
    const float* fc0_t   = (const float*)d_in[16];
    const float* fc1_w   = (const float*)d_in[17];
    const float* fc1_b   = (const float*)d_in[18];
    const float* fc1_s   = (const float*)d_in[19];
    const float* fc1_t   = (const float*)d_in[20];
    const float* fc2_w   = (const float*)d_in[21];
    const float* fc2_b   = (const float*)d_in[22];
    const float* fc2_s   = (const float*)d_in[23];
    const float* fc2_t   = (const float*)d_in[24];
    float* out = (float*)d_out;

    char* ws = (char*)d_ws;
    const int B = 16, N = NPTS;
    // ws layout (bytes) — D overlays U+T (disjoint lifetimes):
    float* Hc   = (float*)(ws + 0);           // [16][320][2048]  41,943,040 B
    float* U    = (float*)(ws + 41943040);    // [16][2048][128]  16,777,216 B
    float* T    = (float*)(ws + 58720256);    // [16][128][2048]  16,777,216 B
    float* D    = (float*)(ws + 41943040);    // [2][2048][2048]  33,554,432 B (overlays U,T)
    int*   I    = (int*)  (ws + 75497472);    // [16][2048][20]    2,621,440 B
    unsigned* M = (unsigned*)(ws + 78118912); // [16][1024]           65,536 B
    // sq[b][m] lives in Hc channel 319 (dead until layer-3 gathermax)
    float* sqBuf = Hc + (size_t)319 * N;      // batch stride 320*N

    dim3 blk(256);
    const int bsX0 = 3 * N, bsH = 320 * N;

    // ---- Layer 0 (C=3 -> F=64): fused select, no D ----
    select0_kernel<<<dim3(B * N / 4), blk, 0, stream>>>(x, I);
    ut_kernel<64, 3><<<dim3(N / 64, 1, B), blk, 0, stream>>>(x, bsX0, ec0_w, ec0_b, U, T);
    gathermax_kernel<64><<<dim3(N / 256, B), blk, 0, stream>>>(U, T, I, Hc, bsH);

    // ---- Layers 1..3 (C=64) ----
    const float* Xin[3] = {Hc, Hc + (size_t)64 * N, Hc + (size_t)128 * N};
    const float* ecw[3] = {ec1_w, ec2_w, ec3_w};
    const float* ecb[3] = {ec1_b, ec2_b, ec3_b};
    for (int L = 0; L < 3; ++L) {
        sq_kernel<64><<<dim3(N / 256, B), blk, 0, stream>>>(Xin[L], bsH, sqBuf, bsH);
        for (int p = 0; p < 8; ++p) {
            distgemm_kernel<64><<<dim3(N / 64, N / 64, 2), blk, 0, stream>>>(
                Xin[L], bsH, 2 * p, sqBuf, bsH, D);
            select_kernel<<<dim3(2 * N / 4), blk, 0, stream>>>(D, 2 * p, I);
        }
        if (L < 2) {
            ut_kernel<64, 64><<<dim3(N / 64, 1, B), blk, 0, stream>>>(Xin[L], bsH, ecw[L], ecb[L], U, T);
            gathermax_kernel<64><<<dim3(N / 256, B), blk, 0, stream>>>(
                U, T, I, Hc + (size_t)(64 * (L + 1)) * N, bsH);
        } else {
            ut_kernel<128, 64><<<dim3(N / 64, 2, B), blk, 0, stream>>>(Xin[L], bsH, ecw[L], ecb[L], U, T);
            gathermax_kernel<128><<<dim3(N / 256, B), blk, 0, stream>>>(
                U, T, I, Hc + (size_t)192 * N, bsH);
        }
    }

    // ---- conv0 + global max (fused) ----
    (void)hipMemsetAsync(M, 0, B * 1024 * sizeof(unsigned), stream);
    conv0max_kernel<<<dim3(N / 128, 1024 / 64, B), blk, 0, stream>>>(Hc, conv0_w, M);

    // ---- head ----
    fc_kernel<<<dim3(B), blk, 0, stream>>>(M, conv0_b, conv0_s, conv0_t,
                                           fc0_w, fc0_b, fc0_s, fc0_t,
                                           fc1_w, fc1_b, fc1_s, fc1_t,
                                           fc2_w, fc2_b, fc2_s, fc2_t, out);
}

// Round 3
// 1499.838 us; speedup vs baseline: 2.4160x; 1.7114x over previous
//
#include <hip/hip_runtime.h>

#define DEVINL __device__ __forceinline__

static const int NPTS = 2048;

DEVINL unsigned fenc(float x) {
    int b = __float_as_int(x);
    return (b < 0) ? ~(unsigned)b : ((unsigned)b | 0x80000000u);
}
DEVINL float fdec(unsigned u) {
    return (u & 0x80000000u) ? __int_as_float((int)(u & 0x7fffffffu))
                             : __int_as_float((int)~u);
}
DEVINL unsigned long long u64min(unsigned long long a, unsigned long long b) {
    return (b < a) ? b : a;
}

// ---------------------------------------------------------------------------
// Exact top-20 of a row held as v[32] per lane (col(j) = lane*4+(j&3)+(j>>2)*256).
// Phase A: tau = 20th smallest of the 64 lane-minima (provable upper bound on
// the true 20th distance). Phase B: ballot-compact all values <= tau (E~25)
// into LDS, bitonic-sort their u64 (fenc(d)<<32|idx) keys across 64 lanes,
// emit lanes 0..19. Keys unique => exact (d,idx) argsort set. Fallback to the
// full 20-iteration tournament when >64 candidates (ties/clusters; rare).
// ---------------------------------------------------------------------------
DEVINL void topk20(float v[32], unsigned long long* cand, int lane,
                   int* __restrict__ Iout, int outBase) {
    // lane-local min tree
    float t16[16];
#pragma unroll
    for (int i = 0; i < 16; ++i) t16[i] = fminf(v[i], v[i + 16]);
#pragma unroll
    for (int i = 0; i < 8; ++i) t16[i] = fminf(t16[i], t16[i + 8]);
#pragma unroll
    for (int i = 0; i < 4; ++i) t16[i] = fminf(t16[i], t16[i + 4]);
    float s = fminf(fminf(t16[0], t16[1]), fminf(t16[2], t16[3]));
    // bitonic sort of 64 lane minima (ascending by lane)
#pragma unroll
    for (int k = 2; k <= 64; k <<= 1) {
#pragma unroll
        for (int j = k >> 1; j >= 1; j >>= 1) {
            float o = __shfl_xor(s, j);
            bool keepmin = (((lane & j) == 0) == ((lane & k) == 0));
            s = keepmin ? fminf(s, o) : fmaxf(s, o);
        }
    }
    const float tau = __shfl(s, 19);
    // compact candidates (v <= tau) into LDS
    int cnt = 0;
#pragma unroll
    for (int j = 0; j < 32; ++j) {
        bool pass = (v[j] <= tau);
        unsigned long long mask = __ballot(pass);
        if (pass) {
            int pos = cnt + (int)__popcll(mask & ((1ull << lane) - 1ull));
            if (pos < 64) {
                int col = lane * 4 + (j & 3) + ((j >> 2) << 8);
                cand[pos] = ((unsigned long long)fenc(v[j]) << 32) | (unsigned)col;
            }
        }
        cnt += (int)__popcll(mask);
    }
    if (cnt <= 64) {
        unsigned long long key = (lane < cnt) ? cand[lane] : ~0ull;
#pragma unroll
        for (int k = 2; k <= 64; k <<= 1) {
#pragma unroll
            for (int j = k >> 1; j >= 1; j >>= 1) {
                unsigned long long o = __shfl_xor(key, j);
                bool keepmin = (((lane & j) == 0) == ((lane & k) == 0));
                unsigned long long mn = u64min(key, o);
                unsigned long long mx = (key ^ o) ^ mn;
                key = keepmin ? mn : mx;
            }
        }
        if (lane < 20) Iout[outBase + lane] = (int)(unsigned)(key & 0xffffffffu);
    } else {
        // exact fallback: 20 sequential tournament extractions
        unsigned long long vk[32];
#pragma unroll
        for (int j = 0; j < 32; ++j) {
            int col = lane * 4 + (j & 3) + ((j >> 2) << 8);
            vk[j] = ((unsigned long long)fenc(v[j]) << 32) | (unsigned)col;
        }
        unsigned long long last = 0ull;
        for (int it = 0; it < 20; ++it) {
            unsigned long long q16[16];
#pragma unroll
            for (int i = 0; i < 16; ++i) {
                unsigned long long a = (vk[i] > last) ? vk[i] : ~0ull;
                unsigned long long c = (vk[i + 16] > last) ? vk[i + 16] : ~0ull;
                q16[i] = u64min(a, c);
            }
#pragma unroll
            for (int i = 0; i < 8; ++i) q16[i] = u64min(q16[i], q16[i + 8]);
#pragma unroll
            for (int i = 0; i < 4; ++i) q16[i] = u64min(q16[i], q16[i + 4]);
            unsigned long long best = u64min(u64min(q16[0], q16[1]), u64min(q16[2], q16[3]));
#pragma unroll
            for (int off = 32; off >= 1; off >>= 1) {
                unsigned long long o = __shfl_down(best, off);
                best = u64min(best, o);
            }
            best = __shfl(best, 0);
            if (lane == 0) Iout[outBase + it] = (int)(unsigned)(best & 0xffffffffu);
            last = best;
        }
    }
}

// ---------------------------------------------------------------------------
// sq: sq[b][m] = sum_c X[b][c][m]^2.
// ---------------------------------------------------------------------------
template<int C>
__global__ __launch_bounds__(256) void sq_kernel(const float* __restrict__ X, int bs,
                                                 float* __restrict__ sqOut, int sqStride) {
    const int b = blockIdx.y;
    const int m = blockIdx.x * 256 + threadIdx.x;
    const float* __restrict__ Xb = X + (size_t)b * bs;
    float s = 0.f;
#pragma unroll 8
    for (int c = 0; c < C; ++c) { float v = Xb[(size_t)c * NPTS + m]; s += v * v; }
    sqOut[(size_t)b * sqStride + m] = s;
}

// ---------------------------------------------------------------------------
// dist GEMM: 128x128 tile, 8x8 micro-tile. D[bb][n][m] = sq[m] - 2 x_n.x_m.
// ---------------------------------------------------------------------------
template<int C>
__global__ __launch_bounds__(256) void distgemm_kernel(const float* __restrict__ X, int bs, int b0,
                                                       const float* __restrict__ sqB, int sqStride,
                                                       float* __restrict__ D) {
    const int N = NPTS;
    __shared__ float As[C][128];
    __shared__ float Bs[C][128];
    const int bb = blockIdx.z, b = b0 + bb;
    const int n0 = blockIdx.y * 128, m0 = blockIdx.x * 128;
    const float* __restrict__ Xb = X + (size_t)b * bs;
    const int tid = threadIdx.x;
    for (int i = tid; i < C * 32; i += 256) {
        int c = i >> 5, q = i & 31;
        ((float4*)&As[c][0])[q] = *(const float4*)&Xb[(size_t)c * N + n0 + q * 4];
        ((float4*)&Bs[c][0])[q] = *(const float4*)&Xb[(size_t)c * N + m0 + q * 4];
    }
    __syncthreads();
    const int nt = tid >> 4, mt = tid & 15;
    float acc[8][8];
#pragma unroll
    for (int i = 0; i < 8; ++i)
#pragma unroll
        for (int j = 0; j < 8; ++j) acc[i][j] = 0.f;
#pragma unroll 4
    for (int c = 0; c < C; ++c) {
        float4 a0 = *(const float4*)&As[c][nt * 8];
        float4 a1 = *(const float4*)&As[c][nt * 8 + 4];
        float4 p0 = *(const float4*)&Bs[c][mt * 8];
        float4 p1 = *(const float4*)&Bs[c][mt * 8 + 4];
        float av[8] = {a0.x, a0.y, a0.z, a0.w, a1.x, a1.y, a1.z, a1.w};
        float bv[8] = {p0.x, p0.y, p0.z, p0.w, p1.x, p1.y, p1.z, p1.w};
#pragma unroll
        for (int i = 0; i < 8; ++i)
#pragma unroll
            for (int j = 0; j < 8; ++j) acc[i][j] += av[i] * bv[j];
    }
    const float* __restrict__ sqp = sqB + (size_t)b * sqStride;
    float4 s0 = *(const float4*)&sqp[m0 + mt * 8];
    float4 s1 = *(const float4*)&sqp[m0 + mt * 8 + 4];
    float sv[8] = {s0.x, s0.y, s0.z, s0.w, s1.x, s1.y, s1.z, s1.w};
#pragma unroll
    for (int i = 0; i < 8; ++i) {
        int row = n0 + nt * 8 + i;
        float* dp = &D[((size_t)bb * N + row) * N + m0 + mt * 8];
        float4 o0 = make_float4(sv[0] - 2.f * acc[i][0], sv[1] - 2.f * acc[i][1],
                                sv[2] - 2.f * acc[i][2], sv[3] - 2.f * acc[i][3]);
        float4 o1 = make_float4(sv[4] - 2.f * acc[i][4], sv[5] - 2.f * acc[i][5],
                                sv[6] - 2.f * acc[i][6], sv[7] - 2.f * acc[i][7]);
        *(float4*)&dp[0] = o0;
        *(float4*)&dp[4] = o1;
    }
}

// ---------------------------------------------------------------------------
// select: one wave per row, reads D row, runs topk20.
// ---------------------------------------------------------------------------
__global__ __launch_bounds__(256) void select_kernel(const float* __restrict__ D, int b0,
                                                     int* __restrict__ Iout) {
    const int N = NPTS, K = 20;
    __shared__ unsigned long long cand[4][64];
    const int w = threadIdx.x >> 6, lane = threadIdx.x & 63;
    const int rowg = blockIdx.x * 4 + w;
    const int bb = rowg >> 11, n = rowg & 2047, b = b0 + bb;
    const float* __restrict__ rp = D + ((size_t)bb * N + n) * N;
    const float INF = __builtin_inff();
    float v[32];
#pragma unroll
    for (int q = 0; q < 8; ++q) {
        const int base = lane * 4 + q * 256;
        float4 x4 = *(const float4*)&rp[base];
        v[q * 4 + 0] = (base + 0 == n) ? INF : x4.x;
        v[q * 4 + 1] = (base + 1 == n) ? INF : x4.y;
        v[q * 4 + 2] = (base + 2 == n) ? INF : x4.z;
        v[q * 4 + 3] = (base + 3 == n) ? INF : x4.w;
    }
    topk20(v, cand[w], lane, Iout, (b * N + n) * K);
}

// ---------------------------------------------------------------------------
// select0: layer-0 fused (C=3) — computes scores inline.
// ---------------------------------------------------------------------------
__global__ __launch_bounds__(256) void select0_kernel(const float* __restrict__ X,
                                                      int* __restrict__ Iout) {
    const int N = NPTS, K = 20;
    __shared__ unsigned long long cand[4][64];
    const int w = threadIdx.x >> 6, lane = threadIdx.x & 63;
    const int rowg = blockIdx.x * 4 + w;
    const int b = rowg >> 11, n = rowg & 2047;
    const float* __restrict__ Xb = X + (size_t)b * 3 * N;
    const float xr = Xb[n], yr = Xb[N + n], zr = Xb[2 * N + n];
    const float INF = __builtin_inff();
    float v[32];
#pragma unroll
    for (int q = 0; q < 8; ++q) {
        const int base = lane * 4 + q * 256;
        const float4 xm = *(const float4*)&Xb[base];
        const float4 ym = *(const float4*)&Xb[N + base];
        const float4 zm = *(const float4*)&Xb[2 * N + base];
        float mx[4] = {xm.x, xm.y, xm.z, xm.w};
        float my[4] = {ym.x, ym.y, ym.z, ym.w};
        float mz[4] = {zm.x, zm.y, zm.z, zm.w};
#pragma unroll
        for (int j = 0; j < 4; ++j) {
            float sq = mx[j] * mx[j] + my[j] * my[j] + mz[j] * mz[j];
            float dot = xr * mx[j] + yr * my[j] + zr * mz[j];
            float d = sq - 2.f * dot;
            v[q * 4 + j] = (base + j == n) ? INF : d;
        }
    }
    topk20(v, cand[w], lane, Iout, (b * N + n) * K);
}

// ---------------------------------------------------------------------------
// U/T GEMMs (unchanged).
// ---------------------------------------------------------------------------
template<int F, int C>
__global__ __launch_bounds__(256) void ut_kernel(const float* __restrict__ X, int bs,
                                                 const float* __restrict__ W,
                                                 const float* __restrict__ bias,
                                                 float* __restrict__ U, float* __restrict__ T) {
    const int N = NPTS;
    __shared__ float Ws2[64][C + 1];
    __shared__ float Wsd[64][C + 1];
    const int n0 = blockIdx.x * 64, f0 = blockIdx.y * 64, b = blockIdx.z;
    const int tid = threadIdx.x;
    for (int i = tid; i < 64 * C; i += 256) {
        int ff = i / C, c = i - ff * C;
        float w1 = W[(f0 + ff) * (2 * C) + c];
        float w2 = W[(f0 + ff) * (2 * C) + C + c];
        Ws2[ff][c] = w2;
        Wsd[ff][c] = w1 - w2;
    }
    __syncthreads();
    const int nt = tid & 15, fg = tid >> 4;
    const float* __restrict__ Xb = X + (size_t)b * bs;
    float au[4][4], av[4][4];
#pragma unroll
    for (int i = 0; i < 4; ++i)
#pragma unroll
        for (int j = 0; j < 4; ++j) { au[i][j] = 0.f; av[i][j] = 0.f; }
#pragma unroll 4
    for (int c = 0; c < C; ++c) {
        const float4 xv = *(const float4*)&Xb[(size_t)c * N + n0 + nt * 4];
#pragma unroll
        for (int fi = 0; fi < 4; ++fi) {
            float w2v = Ws2[fg * 4 + fi][c];
            float wdv = Wsd[fg * 4 + fi][c];
            au[fi][0] += w2v * xv.x; au[fi][1] += w2v * xv.y;
            au[fi][2] += w2v * xv.z; au[fi][3] += w2v * xv.w;
            av[fi][0] += wdv * xv.x; av[fi][1] += wdv * xv.y;
            av[fi][2] += wdv * xv.z; av[fi][3] += wdv * xv.w;
        }
    }
#pragma unroll
    for (int ni = 0; ni < 4; ++ni) {
        int n = n0 + nt * 4 + ni;
        float4 uv = make_float4(au[0][ni], au[1][ni], au[2][ni], au[3][ni]);
        *(float4*)&U[((size_t)b * N + n) * F + f0 + fg * 4] = uv;
    }
#pragma unroll
    for (int fi = 0; fi < 4; ++fi) {
        int f = f0 + fg * 4 + fi;
        float bv = bias[f];
        float4 tv = make_float4(av[fi][0] + bv, av[fi][1] + bv, av[fi][2] + bv, av[fi][3] + bv);
        *(float4*)&T[((size_t)b * F + f) * N + n0 + nt * 4] = tv;
    }
}

// ---------------------------------------------------------------------------
// Gather-max: block = 32 points x 8 f-groups (per-thread F/8 features).
// ---------------------------------------------------------------------------
template<int F>
__global__ __launch_bounds__(256) void gathermax_kernel(const float* __restrict__ U,
                                                        const float* __restrict__ T,
                                                        const int* __restrict__ idx,
                                                        float* __restrict__ Y, int bsY) {
    const int N = NPTS, K = 20, FG = F / 8;
    __shared__ int sidx[32 * 20];
    const int b = blockIdx.y, n0 = blockIdx.x * 32, tid = threadIdx.x;
    const int p = tid >> 3, fg = tid & 7;
    for (int t = tid; t < 32 * K; t += 256) sidx[t] = idx[(b * N + n0) * K + t];
    __syncthreads();
    const int n = n0 + p;
    const float* __restrict__ Ub = U + (size_t)b * N * F;
    const int fbase = fg * FG;
    float mx[FG];
#pragma unroll
    for (int i = 0; i < FG; ++i) mx[i] = -__builtin_inff();
#pragma unroll 4
    for (int j = 0; j < K; ++j) {
        const int r = sidx[p * K + j];
        const float4* up = (const float4*)&Ub[(size_t)r * F + fbase];
#pragma unroll
        for (int q = 0; q < FG / 4; ++q) {
            float4 a = up[q];
            mx[q * 4 + 0] = fmaxf(mx[q * 4 + 0], a.x);
            mx[q * 4 + 1] = fmaxf(mx[q * 4 + 1], a.y);
            mx[q * 4 + 2] = fmaxf(mx[q * 4 + 2], a.z);
            mx[q * 4 + 3] = fmaxf(mx[q * 4 + 3], a.w);
        }
    }
#pragma unroll
    for (int i = 0; i < FG; ++i) {
        const int f = fbase + i;
        float tv = T[((size_t)b * F + f) * N + n];
        Y[(size_t)b * bsY + (size_t)f * N + n] = tv + mx[i];
    }
}

// ---------------------------------------------------------------------------
// conv0 + global max: 128f x 128n tile, 8x8 micro-tile, W transposed in LDS.
// ---------------------------------------------------------------------------
__global__ __launch_bounds__(256) void conv0max_kernel(const float* __restrict__ Hbuf,
                                                       const float* __restrict__ W,
                                                       unsigned* __restrict__ M) {
    const int N = NPTS;
    __shared__ float Hs[32][128];
    __shared__ float Wst[32][132];
    const int n0 = blockIdx.x * 128, f0 = blockIdx.y * 128, b = blockIdx.z;
    const int tid = threadIdx.x, ft = tid >> 4, ntn = tid & 15;
    float acc[8][8];  // [f][n]
#pragma unroll
    for (int i = 0; i < 8; ++i)
#pragma unroll
        for (int j = 0; j < 8; ++j) acc[i][j] = 0.f;

    for (int c0 = 0; c0 < 320; c0 += 32) {
        for (int i = tid; i < 32 * 32; i += 256) {
            int c = i >> 5, q = i & 31;
            ((float4*)&Hs[c][0])[q] =
                *(const float4*)&Hbuf[((size_t)b * 320 + c0 + c) * N + n0 + q * 4];
        }
        for (int i = tid; i < 128 * 8; i += 256) {
            int ff = i >> 3, q = i & 7;
            float4 wv = *(const float4*)&W[(size_t)(f0 + ff) * 320 + c0 + q * 4];
            Wst[q * 4 + 0][ff] = wv.x;
            Wst[q * 4 + 1][ff] = wv.y;
            Wst[q * 4 + 2][ff] = wv.z;
            Wst[q * 4 + 3][ff] = wv.w;
        }
        __syncthreads();
#pragma unroll 4
        for (int ci = 0; ci < 32; ++ci) {
            float4 h0 = *(const float4*)&Hs[ci][ntn * 8];
            float4 h1 = *(const float4*)&Hs[ci][ntn * 8 + 4];
            float4 w0 = *(const float4*)&Wst[ci][ft * 8];
            float4 w1 = *(const float4*)&Wst[ci][ft * 8 + 4];
            float hv[8] = {h0.x, h0.y, h0.z, h0.w, h1.x, h1.y, h1.z, h1.w};
            float wv[8] = {w0.x, w0.y, w0.z, w0.w, w1.x, w1.y, w1.z, w1.w};
#pragma unroll
            for (int fi = 0; fi < 8; ++fi)
#pragma unroll
                for (int nj = 0; nj < 8; ++nj) acc[fi][nj] += wv[fi] * hv[nj];
        }
        __syncthreads();
    }
#pragma unroll
    for (int fi = 0; fi < 8; ++fi) {
        float m = acc[fi][0];
#pragma unroll
        for (int j = 1; j < 8; ++j) m = fmaxf(m, acc[fi][j]);
        for (int off = 8; off >= 1; off >>= 1) m = fmaxf(m, __shfl_down(m, off, 16));
        if (ntn == 0) atomicMax(&M[(b << 10) + f0 + ft * 8 + fi], fenc(m));
    }
}

// ---------------------------------------------------------------------------
// Fused head (unchanged).
// ---------------------------------------------------------------------------
__global__ __launch_bounds__(256) void fc_kernel(const unsigned* __restrict__ M,
    const float* __restrict__ cb, const float* __restrict__ cs, const float* __restrict__ ct,
    const float* __restrict__ w0, const float* __restrict__ b0, const float* __restrict__ s0, const float* __restrict__ t0,
    const float* __restrict__ w1, const float* __restrict__ b1, const float* __restrict__ s1, const float* __restrict__ t1,
    const float* __restrict__ w2, const float* __restrict__ b2, const float* __restrict__ s2, const float* __restrict__ t2,
    float* __restrict__ out) {
    __shared__ float g0[1024], g1[512], g2[256];
    const int b = blockIdx.x, tid = threadIdx.x;
    for (int f = tid; f < 1024; f += 256) {
        float z = fdec(M[b * 1024 + f]);
        float g = cs[f] * (z + cb[f]) + ct[f];
        g0[f] = fmaxf(g, 0.f);
    }
    __syncthreads();
    for (int f = tid; f < 512; f += 256) {
        const float4* wp = (const float4*)(w0 + (size_t)f * 1024);
        float acc = 0.f;
#pragma unroll 4
        for (int c = 0; c < 256; ++c) {
            float4 wv = wp[c];
            float4 gv = *(const float4*)&g0[c * 4];
            acc += wv.x * gv.x + wv.y * gv.y + wv.z * gv.z + wv.w * gv.w;
        }
        float g = s0[f] * (acc + b0[f]) + t0[f];
        g1[f] = fmaxf(g, 0.f);
    }
    __syncthreads();
    if (tid < 256) {
        const float4* wp = (const float4*)(w1 + (size_t)tid * 512);
        float acc = 0.f;
#pragma unroll 4
        for (int c = 0; c < 128; ++c) {
            float4 wv = wp[c];
            float4 gv = *(const float4*)&g1[c * 4];
            acc += wv.x * gv.x + wv.y * gv.y + wv.z * gv.z + wv.w * gv.w;
        }
        float g = s1[tid] * (acc + b1[tid]) + t1[tid];
        g2[tid] = fmaxf(g, 0.f);
    }
    __syncthreads();
    if (tid < 40) {
        const float4* wp = (const float4*)(w2 + (size_t)tid * 256);
        float acc = 0.f;
#pragma unroll 4
        for (int c = 0; c < 64; ++c) {
            float4 wv = wp[c];
            float4 gv = *(const float4*)&g2[c * 4];
            acc += wv.x * gv.x + wv.y * gv.y + wv.z * gv.z + wv.w * gv.w;
        }
        float g = s2[tid] * (acc + b2[tid]) + t2[tid];
        out[b * 40 + tid] = fmaxf(g, 0.f);
    }
}

// ---------------------------------------------------------------------------
extern "C" void kernel_launch(void* const* d_in, const int* in_sizes, int n_in,
                              void* d_out, int out_size, void* d_ws, size_t ws_size,
                              hipStream_t stream) {
    const float* x       = (const float*)d_in[0];
    const float* ec0_w   = (const float*)d_in[1];
    const float* ec0_b   = (const float*)d_in[2];
    const float* ec1_w   = (const float*)d_in[3];
    const float* ec1_b   = (const float*)d_in[4];
    const float* ec2_w   = (const float*)d_in[5];
    const float* ec2_b   = (const float*)d_in[6];
    const float* ec3_w   = (const float*)d_in[7];
    const float* ec3_b   = (const float*)d_in[8];
    const float* conv0_w = (const float*)d_in[9];
    const float* conv0_b = (const float*)d_in[10];
    const float* conv0_s = (const float*)d_in[11];
    const float* conv0_t = (const float*)d_in[12];
    const float* fc0_w   = (const float*)d_in[13];
    const float* fc0_b   = (const float*)d_in[14];
    const float* fc0_s   = (const float*)d_in[15];
    const float* fc0_t   = (const float*)d_in[16];
    const float* fc1_w   = (const float*)d_in[17];
    const float* fc1_b   = (const float*)d_in[18];
    const float* fc1_s   = (const float*)d_in[19];
    const float* fc1_t   = (const float*)d_in[20];
    const float* fc2_w   = (const float*)d_in[21];
    const float* fc2_b   = (const float*)d_in[22];
    const float* fc2_s   = (const float*)d_in[23];
    const float* fc2_t   = (const float*)d_in[24];
    float* out = (float*)d_out;

    char* ws = (char*)d_ws;
    const int B = 16, N = NPTS;
    // ws layout (bytes) — D overlays U+T (disjoint lifetimes):
    float* Hc   = (float*)(ws + 0);           // [16][320][2048]  41,943,040 B
    float* U    = (float*)(ws + 41943040);    // [16][2048][128]  16,777,216 B
    float* T    = (float*)(ws + 58720256);    // [16][128][2048]  16,777,216 B
    float* D    = (float*)(ws + 41943040);    // [2][2048][2048]  33,554,432 B (overlays U,T)
    int*   I    = (int*)  (ws + 75497472);    // [16][2048][20]    2,621,440 B
    unsigned* M = (unsigned*)(ws + 78118912); // [16][1024]           65,536 B
    // sq[b][m] lives in Hc channel 319 (dead until layer-3 gathermax)
    float* sqBuf = Hc + (size_t)319 * N;      // batch stride 320*N

    dim3 blk(256);
    const int bsX0 = 3 * N, bsH = 320 * N;

    // ---- Layer 0 (C=3 -> F=64): fused select, no D ----
    select0_kernel<<<dim3(B * N / 4), blk, 0, stream>>>(x, I);
    ut_kernel<64, 3><<<dim3(N / 64, 1, B), blk, 0, stream>>>(x, bsX0, ec0_w, ec0_b, U, T);
    gathermax_kernel<64><<<dim3(N / 32, B), blk, 0, stream>>>(U, T, I, Hc, bsH);

    // ---- Layers 1..3 (C=64) ----
    const float* Xin[3] = {Hc, Hc + (size_t)64 * N, Hc + (size_t)128 * N};
    const float* ecw[3] = {ec1_w, ec2_w, ec3_w};
    const float* ecb[3] = {ec1_b, ec2_b, ec3_b};
    for (int L = 0; L < 3; ++L) {
        sq_kernel<64><<<dim3(N / 256, B), blk, 0, stream>>>(Xin[L], bsH, sqBuf, bsH);
        for (int p = 0; p < 8; ++p) {
            distgemm_kernel<64><<<dim3(N / 128, N / 128, 2), blk, 0, stream>>>(
                Xin[L], bsH, 2 * p, sqBuf, bsH, D);
            select_kernel<<<dim3(2 * N / 4), blk, 0, stream>>>(D, 2 * p, I);
        }
        if (L < 2) {
            ut_kernel<64, 64><<<dim3(N / 64, 1, B), blk, 0, stream>>>(Xin[L], bsH, ecw[L], ecb[L], U, T);
            gathermax_kernel<64><<<dim3(N / 32, B), blk, 0, stream>>>(
                U, T, I, Hc + (size_t)(64 * (L + 1)) * N, bsH);
        } else {
            ut_kernel<128, 64><<<dim3(N / 64, 2, B), blk, 0, stream>>>(Xin[L], bsH, ecw[L], ecb[L], U, T);
            gathermax_kernel<128><<<dim3(N / 32, B), blk, 0, stream>>>(
                U, T, I, Hc + (size_t)192 * N, bsH);
        }
    }

    // ---- conv0 + global max (fused) ----
    (void)hipMemsetAsync(M, 0, B * 1024 * sizeof(unsigned), stream);
    conv0max_kernel<<<dim3(N / 128, 1024 / 128, B), blk, 0, stream>>>(Hc, conv0_w, M);

    // ---- head ----
    fc_kernel<<<dim3(B), blk, 0, stream>>>(M, conv0_b, conv0_s, conv0_t,
                                           fc0_w, fc0_b, fc0_s, fc0_t,
                                           fc1_w, fc1_b, fc1_s, fc1_t,
                                           fc2_w, fc2_b, fc2_s, fc2_t, out);
}

// Round 4
// 1153.408 us; speedup vs baseline: 3.1417x; 1.3004x over previous
//
#include <hip/hip_runtime.h>

#define DEVINL __device__ __forceinline__

static const int NPTS = 2048;

DEVINL unsigned fenc(float x) {
    int b = __float_as_int(x);
    return (b < 0) ? ~(unsigned)b : ((unsigned)b | 0x80000000u);
}
DEVINL float fdec(unsigned u) {
    return (u & 0x80000000u) ? __int_as_float((int)(u & 0x7fffffffu))
                             : __int_as_float((int)~u);
}
DEVINL unsigned long long u64min(unsigned long long a, unsigned long long b) {
    return (b < a) ? b : a;
}

// ---------------------------------------------------------------------------
// Exact top-20 of a row held as v[32] per lane (col(j) = lane*4+(j&3)+(j>>2)*256).
// tau = 20th smallest of the 64 lane-minima (provable upper bound on true 20th);
// ballot-compact <=tau (E~25) -> u64 bitonic sort -> lanes 0..19. Fallback to
// 20x tournament when >64 candidates. Keys unique => exact argsort semantics.
// ---------------------------------------------------------------------------
DEVINL void topk20(float v[32], unsigned long long* cand, int lane,
                   int* __restrict__ Iout, int outBase) {
    float t16[16];
#pragma unroll
    for (int i = 0; i < 16; ++i) t16[i] = fminf(v[i], v[i + 16]);
#pragma unroll
    for (int i = 0; i < 8; ++i) t16[i] = fminf(t16[i], t16[i + 8]);
#pragma unroll
    for (int i = 0; i < 4; ++i) t16[i] = fminf(t16[i], t16[i + 4]);
    float s = fminf(fminf(t16[0], t16[1]), fminf(t16[2], t16[3]));
#pragma unroll
    for (int k = 2; k <= 64; k <<= 1) {
#pragma unroll
        for (int j = k >> 1; j >= 1; j >>= 1) {
            float o = __shfl_xor(s, j);
            bool keepmin = (((lane & j) == 0) == ((lane & k) == 0));
            s = keepmin ? fminf(s, o) : fmaxf(s, o);
        }
    }
    const float tau = __shfl(s, 19);
    int cnt = 0;
#pragma unroll
    for (int j = 0; j < 32; ++j) {
        bool pass = (v[j] <= tau);
        unsigned long long mask = __ballot(pass);
        if (pass) {
            int pos = cnt + (int)__popcll(mask & ((1ull << lane) - 1ull));
            if (pos < 64) {
                int col = lane * 4 + (j & 3) + ((j >> 2) << 8);
                cand[pos] = ((unsigned long long)fenc(v[j]) << 32) | (unsigned)col;
            }
        }
        cnt += (int)__popcll(mask);
    }
    if (cnt <= 64) {
        unsigned long long key = (lane < cnt) ? cand[lane] : ~0ull;
#pragma unroll
        for (int k = 2; k <= 64; k <<= 1) {
#pragma unroll
            for (int j = k >> 1; j >= 1; j >>= 1) {
                unsigned long long o = __shfl_xor(key, j);
                bool keepmin = (((lane & j) == 0) == ((lane & k) == 0));
                unsigned long long mn = u64min(key, o);
                unsigned long long mx = (key ^ o) ^ mn;
                key = keepmin ? mn : mx;
            }
        }
        if (lane < 20) Iout[outBase + lane] = (int)(unsigned)(key & 0xffffffffu);
    } else {
        unsigned long long vk[32];
#pragma unroll
        for (int j = 0; j < 32; ++j) {
            int col = lane * 4 + (j & 3) + ((j >> 2) << 8);
            vk[j] = ((unsigned long long)fenc(v[j]) << 32) | (unsigned)col;
        }
        unsigned long long last = 0ull;
        for (int it = 0; it < 20; ++it) {
            unsigned long long q16[16];
#pragma unroll
            for (int i = 0; i < 16; ++i) {
                unsigned long long a = (vk[i] > last) ? vk[i] : ~0ull;
                unsigned long long c = (vk[i + 16] > last) ? vk[i + 16] : ~0ull;
                q16[i] = u64min(a, c);
            }
#pragma unroll
            for (int i = 0; i < 8; ++i) q16[i] = u64min(q16[i], q16[i + 8]);
#pragma unroll
            for (int i = 0; i < 4; ++i) q16[i] = u64min(q16[i], q16[i + 4]);
            unsigned long long best = u64min(u64min(q16[0], q16[1]), u64min(q16[2], q16[3]));
#pragma unroll
            for (int off = 32; off >= 1; off >>= 1) {
                unsigned long long o = __shfl_down(best, off);
                best = u64min(best, o);
            }
            best = __shfl(best, 0);
            if (lane == 0) Iout[outBase + it] = (int)(unsigned)(best & 0xffffffffu);
            last = best;
        }
    }
}

// ---------------------------------------------------------------------------
// sq: sq[b][m] = sum_c X[b][c][m]^2.
// ---------------------------------------------------------------------------
template<int C>
__global__ __launch_bounds__(256) void sq_kernel(const float* __restrict__ X, int bs,
                                                 float* __restrict__ sqOut, int sqStride) {
    const int b = blockIdx.y;
    const int m = blockIdx.x * 256 + threadIdx.x;
    const float* __restrict__ Xb = X + (size_t)b * bs;
    float s = 0.f;
#pragma unroll 8
    for (int c = 0; c < C; ++c) { float v = Xb[(size_t)c * NPTS + m]; s += v * v; }
    sqOut[(size_t)b * sqStride + m] = s;
}

// ---------------------------------------------------------------------------
// Fused KNN (C=64): block owns 8 rows. GEMM 8x2048x64 — A rows in LDS
// (broadcast reads), B streamed from global (L2-resident X batch), distance
// row-block kept entirely in 64 KB LDS, then register topk20 (2 rows/wave).
// Thread t owns cols {t*4..+3} and {1024+t*4..+3} -> 16 B-stride LDS writes
// (2-way bank aliasing = free). No HBM round-trip for distances.
// ---------------------------------------------------------------------------
__global__ __launch_bounds__(256) void knnfused_kernel(const float* __restrict__ X, int bs,
                                                       const float* __restrict__ sqB, int sqStride,
                                                       int* __restrict__ Iout) {
    extern __shared__ char smem[];
    float* Dr = (float*)smem;                                     // [8][2048] 64 KB
    float* As = (float*)(smem + 65536);                           // [64][8]    2 KB
    unsigned long long* cand = (unsigned long long*)(smem + 67584); // [4][64]  2 KB
    const int N = NPTS, K = 20;
    const int b = blockIdx.y, n0 = blockIdx.x * 8;
    const float* __restrict__ Xb = X + (size_t)b * bs;
    const int tid = threadIdx.x;
    if (tid < 128) {
        int c = tid >> 1, r4 = (tid & 1) * 4;
        *(float4*)&As[c * 8 + r4] = *(const float4*)&Xb[(size_t)c * N + n0 + r4];
    }
    __syncthreads();
    const int m0 = tid * 4, m1 = 1024 + tid * 4;
    float acc0[8][4], acc1[8][4];
#pragma unroll
    for (int r = 0; r < 8; ++r)
#pragma unroll
        for (int j = 0; j < 4; ++j) { acc0[r][j] = 0.f; acc1[r][j] = 0.f; }
#pragma unroll 4
    for (int c = 0; c < 64; ++c) {
        float4 b0 = *(const float4*)&Xb[(size_t)c * N + m0];
        float4 b1 = *(const float4*)&Xb[(size_t)c * N + m1];
        float4 a0 = *(const float4*)&As[c * 8];
        float4 a1 = *(const float4*)&As[c * 8 + 4];
        float av[8] = {a0.x, a0.y, a0.z, a0.w, a1.x, a1.y, a1.z, a1.w};
#pragma unroll
        for (int r = 0; r < 8; ++r) {
            acc0[r][0] += av[r] * b0.x; acc0[r][1] += av[r] * b0.y;
            acc0[r][2] += av[r] * b0.z; acc0[r][3] += av[r] * b0.w;
            acc1[r][0] += av[r] * b1.x; acc1[r][1] += av[r] * b1.y;
            acc1[r][2] += av[r] * b1.z; acc1[r][3] += av[r] * b1.w;
        }
    }
    const float* __restrict__ sqp = sqB + (size_t)b * sqStride;
    const float4 sq0 = *(const float4*)&sqp[m0];
    const float4 sq1 = *(const float4*)&sqp[m1];
    const float INF = __builtin_inff();
#pragma unroll
    for (int r = 0; r < 8; ++r) {
        const int n = n0 + r;
        float d0[4] = {sq0.x - 2.f * acc0[r][0], sq0.y - 2.f * acc0[r][1],
                       sq0.z - 2.f * acc0[r][2], sq0.w - 2.f * acc0[r][3]};
        float d1[4] = {sq1.x - 2.f * acc1[r][0], sq1.y - 2.f * acc1[r][1],
                       sq1.z - 2.f * acc1[r][2], sq1.w - 2.f * acc1[r][3]};
#pragma unroll
        for (int j = 0; j < 4; ++j) {
            if (m0 + j == n) d0[j] = INF;
            if (m1 + j == n) d1[j] = INF;
        }
        *(float4*)&Dr[r * N + m0] = make_float4(d0[0], d0[1], d0[2], d0[3]);
        *(float4*)&Dr[r * N + m1] = make_float4(d1[0], d1[1], d1[2], d1[3]);
    }
    __syncthreads();
    const int w = tid >> 6, lane = tid & 63;
#pragma unroll
    for (int rr = 0; rr < 2; ++rr) {
        const int r = w * 2 + rr;
        const float* __restrict__ rp = &Dr[r * N];
        float v[32];
#pragma unroll
        for (int q = 0; q < 8; ++q) {
            float4 x4 = *(const float4*)&rp[lane * 4 + q * 256];
            v[q * 4 + 0] = x4.x; v[q * 4 + 1] = x4.y;
            v[q * 4 + 2] = x4.z; v[q * 4 + 3] = x4.w;
        }
        topk20(v, cand + w * 64, lane, Iout, (b * N + n0 + r) * K);
    }
}

// ---------------------------------------------------------------------------
// select0: layer-0 (C=3) — computes scores inline, register topk.
// ---------------------------------------------------------------------------
__global__ __launch_bounds__(256) void select0_kernel(const float* __restrict__ X,
                                                      int* __restrict__ Iout) {
    const int N = NPTS, K = 20;
    __shared__ unsigned long long cand[4][64];
    const int w = threadIdx.x >> 6, lane = threadIdx.x & 63;
    const int rowg = blockIdx.x * 4 + w;
    const int b = rowg >> 11, n = rowg & 2047;
    const float* __restrict__ Xb = X + (size_t)b * 3 * N;
    const float xr = Xb[n], yr = Xb[N + n], zr = Xb[2 * N + n];
    const float INF = __builtin_inff();
    float v[32];
#pragma unroll
    for (int q = 0; q < 8; ++q) {
        const int base = lane * 4 + q * 256;
        const float4 xm = *(const float4*)&Xb[base];
        const float4 ym = *(const float4*)&Xb[N + base];
        const float4 zm = *(const float4*)&Xb[2 * N + base];
        float mx[4] = {xm.x, xm.y, xm.z, xm.w};
        float my[4] = {ym.x, ym.y, ym.z, ym.w};
        float mz[4] = {zm.x, zm.y, zm.z, zm.w};
#pragma unroll
        for (int j = 0; j < 4; ++j) {
            float sq = mx[j] * mx[j] + my[j] * my[j] + mz[j] * mz[j];
            float dot = xr * mx[j] + yr * my[j] + zr * mz[j];
            float d = sq - 2.f * dot;
            v[q * 4 + j] = (base + j == n) ? INF : d;
        }
    }
    topk20(v, &cand[w][0], lane, Iout, (b * N + n) * K);
}

// ---------------------------------------------------------------------------
// U/T GEMMs (unchanged).
// ---------------------------------------------------------------------------
template<int F, int C>
__global__ __launch_bounds__(256) void ut_kernel(const float* __restrict__ X, int bs,
                                                 const float* __restrict__ W,
                                                 const float* __restrict__ bias,
                                                 float* __restrict__ U, float* __restrict__ T) {
    const int N = NPTS;
    __shared__ float Ws2[64][C + 1];
    __shared__ float Wsd[64][C + 1];
    const int n0 = blockIdx.x * 64, f0 = blockIdx.y * 64, b = blockIdx.z;
    const int tid = threadIdx.x;
    for (int i = tid; i < 64 * C; i += 256) {
        int ff = i / C, c = i - ff * C;
        float w1 = W[(f0 + ff) * (2 * C) + c];
        float w2 = W[(f0 + ff) * (2 * C) + C + c];
        Ws2[ff][c] = w2;
        Wsd[ff][c] = w1 - w2;
    }
    __syncthreads();
    const int nt = tid & 15, fg = tid >> 4;
    const float* __restrict__ Xb = X + (size_t)b * bs;
    float au[4][4], av[4][4];
#pragma unroll
    for (int i = 0; i < 4; ++i)
#pragma unroll
        for (int j = 0; j < 4; ++j) { au[i][j] = 0.f; av[i][j] = 0.f; }
#pragma unroll 4
    for (int c = 0; c < C; ++c) {
        const float4 xv = *(const float4*)&Xb[(size_t)c * N + n0 + nt * 4];
#pragma unroll
        for (int fi = 0; fi < 4; ++fi) {
            float w2v = Ws2[fg * 4 + fi][c];
            float wdv = Wsd[fg * 4 + fi][c];
            au[fi][0] += w2v * xv.x; au[fi][1] += w2v * xv.y;
            au[fi][2] += w2v * xv.z; au[fi][3] += w2v * xv.w;
            av[fi][0] += wdv * xv.x; av[fi][1] += wdv * xv.y;
            av[fi][2] += wdv * xv.z; av[fi][3] += wdv * xv.w;
        }
    }
#pragma unroll
    for (int ni = 0; ni < 4; ++ni) {
        int n = n0 + nt * 4 + ni;
        float4 uv = make_float4(au[0][ni], au[1][ni], au[2][ni], au[3][ni]);
        *(float4*)&U[((size_t)b * N + n) * F + f0 + fg * 4] = uv;
    }
#pragma unroll
    for (int fi = 0; fi < 4; ++fi) {
        int f = f0 + fg * 4 + fi;
        float bv = bias[f];
        float4 tv = make_float4(av[fi][0] + bv, av[fi][1] + bv, av[fi][2] + bv, av[fi][3] + bv);
        *(float4*)&T[((size_t)b * F + f) * N + n0 + nt * 4] = tv;
    }
}

// ---------------------------------------------------------------------------
// Gather-max: block = 32 points x 8 f-groups.
// ---------------------------------------------------------------------------
template<int F>
__global__ __launch_bounds__(256) void gathermax_kernel(const float* __restrict__ U,
                                                        const float* __restrict__ T,
                                                        const int* __restrict__ idx,
                                                        float* __restrict__ Y, int bsY) {
    const int N = NPTS, K = 20, FG = F / 8;
    __shared__ int sidx[32 * 20];
    const int b = blockIdx.y, n0 = blockIdx.x * 32, tid = threadIdx.x;
    const int p = tid >> 3, fg = tid & 7;
    for (int t = tid; t < 32 * K; t += 256) sidx[t] = idx[(b * N + n0) * K + t];
    __syncthreads();
    const int n = n0 + p;
    const float* __restrict__ Ub = U + (size_t)b * N * F;
    const int fbase = fg * FG;
    float mx[FG];
#pragma unroll
    for (int i = 0; i < FG; ++i) mx[i] = -__builtin_inff();
#pragma unroll 4
    for (int j = 0; j < K; ++j) {
        const int r = sidx[p * K + j];
        const float4* up = (const float4*)&Ub[(size_t)r * F + fbase];
#pragma unroll
        for (int q = 0; q < FG / 4; ++q) {
            float4 a = up[q];
            mx[q * 4 + 0] = fmaxf(mx[q * 4 + 0], a.x);
            mx[q * 4 + 1] = fmaxf(mx[q * 4 + 1], a.y);
            mx[q * 4 + 2] = fmaxf(mx[q * 4 + 2], a.z);
            mx[q * 4 + 3] = fmaxf(mx[q * 4 + 3], a.w);
        }
    }
#pragma unroll
    for (int i = 0; i < FG; ++i) {
        const int f = fbase + i;
        float tv = T[((size_t)b * F + f) * N + n];
        Y[(size_t)b * bsY + (size_t)f * N + n] = tv + mx[i];
    }
}

// ---------------------------------------------------------------------------
// conv0 + global max: 128f x 128n tile, 8x8 micro-tile in SPLIT-4 mapping
// (f = ft*4+{0..3} U 64+ft*4+{0..3}, n likewise): LDS reads at 16 B stride ->
// 2-way bank aliasing (free) instead of the 4-way conflicts of stride-32 B.
// ---------------------------------------------------------------------------
__global__ __launch_bounds__(256) void conv0max_kernel(const float* __restrict__ Hbuf,
                                                       const float* __restrict__ W,
                                                       unsigned* __restrict__ M) {
    const int N = NPTS;
    __shared__ float Hs[32][128];
    __shared__ float Wst[32][132];
    const int n0 = blockIdx.x * 128, f0 = blockIdx.y * 128, b = blockIdx.z;
    const int tid = threadIdx.x, ft = tid >> 4, ntn = tid & 15;
    float acc[8][8];  // [f split-4][n split-4]
#pragma unroll
    for (int i = 0; i < 8; ++i)
#pragma unroll
        for (int j = 0; j < 8; ++j) acc[i][j] = 0.f;

    for (int c0 = 0; c0 < 320; c0 += 32) {
        for (int i = tid; i < 32 * 32; i += 256) {
            int c = i >> 5, q = i & 31;
            ((float4*)&Hs[c][0])[q] =
                *(const float4*)&Hbuf[((size_t)b * 320 + c0 + c) * N + n0 + q * 4];
        }
        for (int i = tid; i < 128 * 8; i += 256) {
            int ff = i >> 3, q = i & 7;
            float4 wv = *(const float4*)&W[(size_t)(f0 + ff) * 320 + c0 + q * 4];
            Wst[q * 4 + 0][ff] = wv.x;
            Wst[q * 4 + 1][ff] = wv.y;
            Wst[q * 4 + 2][ff] = wv.z;
            Wst[q * 4 + 3][ff] = wv.w;
        }
        __syncthreads();
#pragma unroll 4
        for (int ci = 0; ci < 32; ++ci) {
            float4 h0 = *(const float4*)&Hs[ci][ntn * 4];
            float4 h1 = *(const float4*)&Hs[ci][64 + ntn * 4];
            float4 w0 = *(const float4*)&Wst[ci][ft * 4];
            float4 w1 = *(const float4*)&Wst[ci][64 + ft * 4];
            float hv[8] = {h0.x, h0.y, h0.z, h0.w, h1.x, h1.y, h1.z, h1.w};
            float wv[8] = {w0.x, w0.y, w0.z, w0.w, w1.x, w1.y, w1.z, w1.w};
#pragma unroll
            for (int fi = 0; fi < 8; ++fi)
#pragma unroll
                for (int nj = 0; nj < 8; ++nj) acc[fi][nj] += wv[fi] * hv[nj];
        }
        __syncthreads();
    }
#pragma unroll
    for (int fi = 0; fi < 8; ++fi) {
        float m = acc[fi][0];
#pragma unroll
        for (int j = 1; j < 8; ++j) m = fmaxf(m, acc[fi][j]);
        for (int off = 8; off >= 1; off >>= 1) m = fmaxf(m, __shfl_down(m, off, 16));
        const int f = f0 + ((fi < 4) ? (ft * 4 + fi) : (64 + ft * 4 + fi - 4));
        if (ntn == 0) atomicMax(&M[(b << 10) + f], fenc(m));
    }
}

// ---------------------------------------------------------------------------
// Fused head (unchanged).
// ---------------------------------------------------------------------------
__global__ __launch_bounds__(256) void fc_kernel(const unsigned* __restrict__ M,
    const float* __restrict__ cb, const float* __restrict__ cs, const float* __restrict__ ct,
    const float* __restrict__ w0, const float* __restrict__ b0, const float* __restrict__ s0, const float* __restrict__ t0,
    const float* __restrict__ w1, const float* __restrict__ b1, const float* __restrict__ s1, const float* __restrict__ t1,
    const float* __restrict__ w2, const float* __restrict__ b2, const float* __restrict__ s2, const float* __restrict__ t2,
    float* __restrict__ out) {
    __shared__ float g0[1024], g1[512], g2[256];
    const int b = blockIdx.x, tid = threadIdx.x;
    for (int f = tid; f < 1024; f += 256) {
        float z = fdec(M[b * 1024 + f]);
        float g = cs[f] * (z + cb[f]) + ct[f];
        g0[f] = fmaxf(g, 0.f);
    }
    __syncthreads();
    for (int f = tid; f < 512; f += 256) {
        const float4* wp = (const float4*)(w0 + (size_t)f * 1024);
        float acc = 0.f;
#pragma unroll 4
        for (int c = 0; c < 256; ++c) {
            float4 wv = wp[c];
            float4 gv = *(const float4*)&g0[c * 4];
            acc += wv.x * gv.x + wv.y * gv.y + wv.z * gv.z + wv.w * gv.w;
        }
        float g = s0[f] * (acc + b0[f]) + t0[f];
        g1[f] = fmaxf(g, 0.f);
    }
    __syncthreads();
    if (tid < 256) {
        const float4* wp = (const float4*)(w1 + (size_t)tid * 512);
        float acc = 0.f;
#pragma unroll 4
        for (int c = 0; c < 128; ++c) {
            float4 wv = wp[c];
            float4 gv = *(const float4*)&g1[c * 4];
            acc += wv.x * gv.x + wv.y * gv.y + wv.z * gv.z + wv.w * gv.w;
        }
        float g = s1[tid] * (acc + b1[tid]) + t1[tid];
        g2[tid] = fmaxf(g, 0.f);
    }
    __syncthreads();
    if (tid < 40) {
        const float4* wp = (const float4*)(w2 + (size_t)tid * 256);
        float acc = 0.f;
#pragma unroll 4
        for (int c = 0; c < 64; ++c) {
            float4 wv = wp[c];
            float4 gv = *(const float4*)&g2[c * 4];
            acc += wv.x * gv.x + wv.y * gv.y + wv.z * gv.z + wv.w * gv.w;
        }
        float g = s2[tid] * (acc + b2[tid]) + t2[tid];
        out[b * 40 + tid] = fmaxf(g, 0.f);
    }
}

// ---------------------------------------------------------------------------
extern "C" void kernel_launch(void* const* d_in, const int* in_sizes, int n_in,
                              void* d_out, int out_size, void* d_ws, size_t ws_size,
                              hipStream_t stream) {
    const float* x       = (const float*)d_in[0];
    const float* ec0_w   = (const float*)d_in[1];
    const float* ec0_b   = (const float*)d_in[2];
    const float* ec1_w   = (const float*)d_in[3];
    const float* ec1_b   = (const float*)d_in[4];
    const float* ec2_w   = (const float*)d_in[5];
    const float* ec2_b   = (const float*)d_in[6];
    const float* ec3_w   = (const float*)d_in[7];
    const float* ec3_b   = (const float*)d_in[8];
    const float* conv0_w = (const float*)d_in[9];
    const float* conv0_b = (const float*)d_in[10];
    const float* conv0_s = (const float*)d_in[11];
    const float* conv0_t = (const float*)d_in[12];
    const float* fc0_w   = (const float*)d_in[13];
    const float* fc0_b   = (const float*)d_in[14];
    const float* fc0_s   = (const float*)d_in[15];
    const float* fc0_t   = (const float*)d_in[16];
    const float* fc1_w   = (const float*)d_in[17];
    const float* fc1_b   = (const float*)d_in[18];
    const float* fc1_s   = (const float*)d_in[19];
    const float* fc1_t   = (const float*)d_in[20];
    const float* fc2_w   = (const float*)d_in[21];
    const float* fc2_b   = (const float*)d_in[22];
    const float* fc2_s   = (const float*)d_in[23];
    const float* fc2_t   = (const float*)d_in[24];
    float* out = (float*)d_out;

    char* ws = (char*)d_ws;
    const int B = 16, N = NPTS;
    float* Hc   = (float*)(ws + 0);           // [16][320][2048]  41,943,040 B
    float* U    = (float*)(ws + 41943040);    // [16][2048][128]  16,777,216 B
    float* T    = (float*)(ws + 58720256);    // [16][128][2048]  16,777,216 B
    int*   I    = (int*)  (ws + 75497472);    // [16][2048][20]    2,621,440 B
    unsigned* M = (unsigned*)(ws + 78118912); // [16][1024]           65,536 B
    // sq[b][m] lives in Hc channel 319 (dead until layer-3 gathermax)
    float* sqBuf = Hc + (size_t)319 * N;      // batch stride 320*N

    (void)hipFuncSetAttribute((const void*)knnfused_kernel,
                              hipFuncAttributeMaxDynamicSharedMemorySize, 69632);

    dim3 blk(256);
    const int bsX0 = 3 * N, bsH = 320 * N;

    // ---- Layer 0 (C=3 -> F=64): fused select, no dist buffer ----
    select0_kernel<<<dim3(B * N / 4), blk, 0, stream>>>(x, I);
    ut_kernel<64, 3><<<dim3(N / 64, 1, B), blk, 0, stream>>>(x, bsX0, ec0_w, ec0_b, U, T);
    gathermax_kernel<64><<<dim3(N / 32, B), blk, 0, stream>>>(U, T, I, Hc, bsH);

    // ---- Layers 1..3 (C=64): fused dist+select (no HBM round-trip) ----
    const float* Xin[3] = {Hc, Hc + (size_t)64 * N, Hc + (size_t)128 * N};
    const float* ecw[3] = {ec1_w, ec2_w, ec3_w};
    const float* ecb[3] = {ec1_b, ec2_b, ec3_b};
    for (int L = 0; L < 3; ++L) {
        sq_kernel<64><<<dim3(N / 256, B), blk, 0, stream>>>(Xin[L], bsH, sqBuf, bsH);
        knnfused_kernel<<<dim3(N / 8, B), blk, 69632, stream>>>(Xin[L], bsH, sqBuf, bsH, I);
        if (L < 2) {
            ut_kernel<64, 64><<<dim3(N / 64, 1, B), blk, 0, stream>>>(Xin[L], bsH, ecw[L], ecb[L], U, T);
            gathermax_kernel<64><<<dim3(N / 32, B), blk, 0, stream>>>(
                U, T, I, Hc + (size_t)(64 * (L + 1)) * N, bsH);
        } else {
            ut_kernel<128, 64><<<dim3(N / 64, 2, B), blk, 0, stream>>>(Xin[L], bsH, ecw[L], ecb[L], U, T);
            gathermax_kernel<128><<<dim3(N / 32, B), blk, 0, stream>>>(
                U, T, I, Hc + (size_t)192 * N, bsH);
        }
    }

    // ---- conv0 + global max (fused) ----
    (void)hipMemsetAsync(M, 0, B * 1024 * sizeof(unsigned), stream);
    conv0max_kernel<<<dim3(N / 128, 1024 / 128, B), blk, 0, stream>>>(Hc, conv0_w, M);

    // ---- head ----
    fc_kernel<<<dim3(B), blk, 0, stream>>>(M, conv0_b, conv0_s, conv0_t,
                                           fc0_w, fc0_b, fc0_s, fc0_t,
                                           fc1_w, fc1_b, fc1_s, fc1_t,
                                           fc2_w, fc2_b, fc2_s, fc2_t, out);
}

// Round 5
// 995.374 us; speedup vs baseline: 3.6405x; 1.1588x over previous
//
#include <hip/hip_runtime.h>

#define DEVINL __device__ __forceinline__

static const int NPTS = 2048;

typedef __attribute__((ext_vector_type(8))) short bf16x8;
typedef __attribute__((ext_vector_type(4))) float f32x4;

DEVINL unsigned fenc(float x) {
    int b = __float_as_int(x);
    return (b < 0) ? ~(unsigned)b : ((unsigned)b | 0x80000000u);
}
DEVINL float fdec(unsigned u) {
    return (u & 0x80000000u) ? __int_as_float((int)(u & 0x7fffffffu))
                             : __int_as_float((int)~u);
}
DEVINL unsigned long long u64min(unsigned long long a, unsigned long long b) {
    return (b < a) ? b : a;
}
DEVINL unsigned short f2bf(float x) {  // round-to-nearest-even bf16 (finite inputs)
    unsigned u = __float_as_uint(x);
    return (unsigned short)((u + 0x7fffu + ((u >> 16) & 1u)) >> 16);
}
DEVINL float bf2f(unsigned short h) { return __uint_as_float(((unsigned)h) << 16); }

// ---------------------------------------------------------------------------
// Exact top-20 of a row held as v[32] per lane (col(j) = lane*4+(j&3)+(j>>2)*256).
// tau = 20th smallest of the 64 lane-minima; ballot-compact <=tau (E~25) ->
// u64 bitonic sort -> lanes 0..19. Fallback to 20x tournament when >64 cands.
// ---------------------------------------------------------------------------
DEVINL void topk20(float v[32], unsigned long long* cand, int lane,
                   int* __restrict__ Iout, int outBase) {
    float t16[16];
#pragma unroll
    for (int i = 0; i < 16; ++i) t16[i] = fminf(v[i], v[i + 16]);
#pragma unroll
    for (int i = 0; i < 8; ++i) t16[i] = fminf(t16[i], t16[i + 8]);
#pragma unroll
    for (int i = 0; i < 4; ++i) t16[i] = fminf(t16[i], t16[i + 4]);
    float s = fminf(fminf(t16[0], t16[1]), fminf(t16[2], t16[3]));
#pragma unroll
    for (int k = 2; k <= 64; k <<= 1) {
#pragma unroll
        for (int j = k >> 1; j >= 1; j >>= 1) {
            float o = __shfl_xor(s, j);
            bool keepmin = (((lane & j) == 0) == ((lane & k) == 0));
            s = keepmin ? fminf(s, o) : fmaxf(s, o);
        }
    }
    const float tau = __shfl(s, 19);
    int cnt = 0;
#pragma unroll
    for (int j = 0; j < 32; ++j) {
        bool pass = (v[j] <= tau);
        unsigned long long mask = __ballot(pass);
        if (pass) {
            int pos = cnt + (int)__popcll(mask & ((1ull << lane) - 1ull));
            if (pos < 64) {
                int col = lane * 4 + (j & 3) + ((j >> 2) << 8);
                cand[pos] = ((unsigned long long)fenc(v[j]) << 32) | (unsigned)col;
            }
        }
        cnt += (int)__popcll(mask);
    }
    if (cnt <= 64) {
        unsigned long long key = (lane < cnt) ? cand[lane] : ~0ull;
#pragma unroll
        for (int k = 2; k <= 64; k <<= 1) {
#pragma unroll
            for (int j = k >> 1; j >= 1; j >>= 1) {
                unsigned long long o = __shfl_xor(key, j);
                bool keepmin = (((lane & j) == 0) == ((lane & k) == 0));
                unsigned long long mn = u64min(key, o);
                unsigned long long mx = (key ^ o) ^ mn;
                key = keepmin ? mn : mx;
            }
        }
        if (lane < 20) Iout[outBase + lane] = (int)(unsigned)(key & 0xffffffffu);
    } else {
        unsigned long long vk[32];
#pragma unroll
        for (int j = 0; j < 32; ++j) {
            int col = lane * 4 + (j & 3) + ((j >> 2) << 8);
            vk[j] = ((unsigned long long)fenc(v[j]) << 32) | (unsigned)col;
        }
        unsigned long long last = 0ull;
        for (int it = 0; it < 20; ++it) {
            unsigned long long q16[16];
#pragma unroll
            for (int i = 0; i < 16; ++i) {
                unsigned long long a = (vk[i] > last) ? vk[i] : ~0ull;
                unsigned long long c = (vk[i + 16] > last) ? vk[i + 16] : ~0ull;
                q16[i] = u64min(a, c);
            }
#pragma unroll
            for (int i = 0; i < 8; ++i) q16[i] = u64min(q16[i], q16[i + 8]);
#pragma unroll
            for (int i = 0; i < 4; ++i) q16[i] = u64min(q16[i], q16[i + 4]);
            unsigned long long best = u64min(u64min(q16[0], q16[1]), u64min(q16[2], q16[3]));
#pragma unroll
            for (int off = 32; off >= 1; off >>= 1) {
                unsigned long long o = __shfl_down(best, off);
                best = u64min(best, o);
            }
            best = __shfl(best, 0);
            if (lane == 0) Iout[outBase + it] = (int)(unsigned)(best & 0xffffffffu);
            last = best;
        }
    }
}

// ---------------------------------------------------------------------------
// Fused KNN (C=64) with inline sq: block owns 8 rows; GEMM 8x2048x64 with A in
// LDS, B streamed (L2-resident); sq[m] accumulated per-thread alongside (same
// ascending-c order as before -> bit-identical distances). Row-block stays in
// LDS; register topk20 (2 rows/wave).
// ---------------------------------------------------------------------------
__global__ __launch_bounds__(256) void knnfused_kernel(const float* __restrict__ X, int bs,
                                                       int* __restrict__ Iout) {
    extern __shared__ char smem[];
    float* Dr = (float*)smem;                                       // [8][2048] 64 KB
    float* As = (float*)(smem + 65536);                             // [64][8]    2 KB
    unsigned long long* cand = (unsigned long long*)(smem + 67584); // [4][64]    2 KB
    const int N = NPTS, K = 20;
    const int b = blockIdx.y, n0 = blockIdx.x * 8;
    const float* __restrict__ Xb = X + (size_t)b * bs;
    const int tid = threadIdx.x;
    if (tid < 128) {
        int c = tid >> 1, r4 = (tid & 1) * 4;
        *(float4*)&As[c * 8 + r4] = *(const float4*)&Xb[(size_t)c * N + n0 + r4];
    }
    __syncthreads();
    const int m0 = tid * 4, m1 = 1024 + tid * 4;
    float acc0[8][4], acc1[8][4], sq0[4], sq1[4];
#pragma unroll
    for (int r = 0; r < 8; ++r)
#pragma unroll
        for (int j = 0; j < 4; ++j) { acc0[r][j] = 0.f; acc1[r][j] = 0.f; }
#pragma unroll
    for (int j = 0; j < 4; ++j) { sq0[j] = 0.f; sq1[j] = 0.f; }
#pragma unroll 4
    for (int c = 0; c < 64; ++c) {
        float4 b0 = *(const float4*)&Xb[(size_t)c * N + m0];
        float4 b1 = *(const float4*)&Xb[(size_t)c * N + m1];
        float4 a0 = *(const float4*)&As[c * 8];
        float4 a1 = *(const float4*)&As[c * 8 + 4];
        sq0[0] += b0.x * b0.x; sq0[1] += b0.y * b0.y;
        sq0[2] += b0.z * b0.z; sq0[3] += b0.w * b0.w;
        sq1[0] += b1.x * b1.x; sq1[1] += b1.y * b1.y;
        sq1[2] += b1.z * b1.z; sq1[3] += b1.w * b1.w;
        float av[8] = {a0.x, a0.y, a0.z, a0.w, a1.x, a1.y, a1.z, a1.w};
#pragma unroll
        for (int r = 0; r < 8; ++r) {
            acc0[r][0] += av[r] * b0.x; acc0[r][1] += av[r] * b0.y;
            acc0[r][2] += av[r] * b0.z; acc0[r][3] += av[r] * b0.w;
            acc1[r][0] += av[r] * b1.x; acc1[r][1] += av[r] * b1.y;
            acc1[r][2] += av[r] * b1.z; acc1[r][3] += av[r] * b1.w;
        }
    }
    const float INF = __builtin_inff();
#pragma unroll
    for (int r = 0; r < 8; ++r) {
        const int n = n0 + r;
        float d0[4] = {sq0[0] - 2.f * acc0[r][0], sq0[1] - 2.f * acc0[r][1],
                       sq0[2] - 2.f * acc0[r][2], sq0[3] - 2.f * acc0[r][3]};
        float d1[4] = {sq1[0] - 2.f * acc1[r][0], sq1[1] - 2.f * acc1[r][1],
                       sq1[2] - 2.f * acc1[r][2], sq1[3] - 2.f * acc1[r][3]};
#pragma unroll
        for (int j = 0; j < 4; ++j) {
            if (m0 + j == n) d0[j] = INF;
            if (m1 + j == n) d1[j] = INF;
        }
        *(float4*)&Dr[r * N + m0] = make_float4(d0[0], d0[1], d0[2], d0[3]);
        *(float4*)&Dr[r * N + m1] = make_float4(d1[0], d1[1], d1[2], d1[3]);
    }
    __syncthreads();
    const int w = tid >> 6, lane = tid & 63;
#pragma unroll
    for (int rr = 0; rr < 2; ++rr) {
        const int r = w * 2 + rr;
        const float* __restrict__ rp = &Dr[r * N];
        float v[32];
#pragma unroll
        for (int q = 0; q < 8; ++q) {
            float4 x4 = *(const float4*)&rp[lane * 4 + q * 256];
            v[q * 4 + 0] = x4.x; v[q * 4 + 1] = x4.y;
            v[q * 4 + 2] = x4.z; v[q * 4 + 3] = x4.w;
        }
        topk20(v, cand + w * 64, lane, Iout, (b * N + n0 + r) * K);
    }
}

// ---------------------------------------------------------------------------
// select0: layer-0 (C=3) — scores inline, register topk.
// ---------------------------------------------------------------------------
__global__ __launch_bounds__(256) void select0_kernel(const float* __restrict__ X,
                                                      int* __restrict__ Iout) {
    const int N = NPTS, K = 20;
    __shared__ unsigned long long cand[4][64];
    const int w = threadIdx.x >> 6, lane = threadIdx.x & 63;
    const int rowg = blockIdx.x * 4 + w;
    const int b = rowg >> 11, n = rowg & 2047;
    const float* __restrict__ Xb = X + (size_t)b * 3 * N;
    const float xr = Xb[n], yr = Xb[N + n], zr = Xb[2 * N + n];
    const float INF = __builtin_inff();
    float v[32];
#pragma unroll
    for (int q = 0; q < 8; ++q) {
        const int base = lane * 4 + q * 256;
        const float4 xm = *(const float4*)&Xb[base];
        const float4 ym = *(const float4*)&Xb[N + base];
        const float4 zm = *(const float4*)&Xb[2 * N + base];
        float mx[4] = {xm.x, xm.y, xm.z, xm.w};
        float my[4] = {ym.x, ym.y, ym.z, ym.w};
        float mz[4] = {zm.x, zm.y, zm.z, zm.w};
#pragma unroll
        for (int j = 0; j < 4; ++j) {
            float sq = mx[j] * mx[j] + my[j] * my[j] + mz[j] * mz[j];
            float dot = xr * mx[j] + yr * my[j] + zr * mz[j];
            float d = sq - 2.f * dot;
            v[q * 4 + j] = (base + j == n) ? INF : d;
        }
    }
    topk20(v, &cand[w][0], lane, Iout, (b * N + n) * K);
}

// ---------------------------------------------------------------------------
// U/T GEMMs (unchanged).
// ---------------------------------------------------------------------------
template<int F, int C>
__global__ __launch_bounds__(256) void ut_kernel(const float* __restrict__ X, int bs,
                                                 const float* __restrict__ W,
                                                 const float* __restrict__ bias,
                                                 float* __restrict__ U, float* __restrict__ T) {
    const int N = NPTS;
    __shared__ float Ws2[64][C + 1];
    __shared__ float Wsd[64][C + 1];
    const int n0 = blockIdx.x * 64, f0 = blockIdx.y * 64, b = blockIdx.z;
    const int tid = threadIdx.x;
    for (int i = tid; i < 64 * C; i += 256) {
        int ff = i / C, c = i - ff * C;
        float w1 = W[(f0 + ff) * (2 * C) + c];
        float w2 = W[(f0 + ff) * (2 * C) + C + c];
        Ws2[ff][c] = w2;
        Wsd[ff][c] = w1 - w2;
    }
    __syncthreads();
    const int nt = tid & 15, fg = tid >> 4;
    const float* __restrict__ Xb = X + (size_t)b * bs;
    float au[4][4], av[4][4];
#pragma unroll
    for (int i = 0; i < 4; ++i)
#pragma unroll
        for (int j = 0; j < 4; ++j) { au[i][j] = 0.f; av[i][j] = 0.f; }
#pragma unroll 4
    for (int c = 0; c < C; ++c) {
        const float4 xv = *(const float4*)&Xb[(size_t)c * N + n0 + nt * 4];
#pragma unroll
        for (int fi = 0; fi < 4; ++fi) {
            float w2v = Ws2[fg * 4 + fi][c];
            float wdv = Wsd[fg * 4 + fi][c];
            au[fi][0] += w2v * xv.x; au[fi][1] += w2v * xv.y;
            au[fi][2] += w2v * xv.z; au[fi][3] += w2v * xv.w;
            av[fi][0] += wdv * xv.x; av[fi][1] += wdv * xv.y;
            av[fi][2] += wdv * xv.z; av[fi][3] += wdv * xv.w;
        }
    }
#pragma unroll
    for (int ni = 0; ni < 4; ++ni) {
        int n = n0 + nt * 4 + ni;
        float4 uv = make_float4(au[0][ni], au[1][ni], au[2][ni], au[3][ni]);
        *(float4*)&U[((size_t)b * N + n) * F + f0 + fg * 4] = uv;
    }
#pragma unroll
    for (int fi = 0; fi < 4; ++fi) {
        int f = f0 + fg * 4 + fi;
        float bv = bias[f];
        float4 tv = make_float4(av[fi][0] + bv, av[fi][1] + bv, av[fi][2] + bv, av[fi][3] + bv);
        *(float4*)&T[((size_t)b * F + f) * N + n0 + nt * 4] = tv;
    }
}

// ---------------------------------------------------------------------------
// Gather-max: block = 32 points x 8 f-groups. Writes fp32 Hc slice (optional,
// needed as next-layer KNN input) AND bf16 hi/lo into Ht[b][n][320] at column
// offset `hoff` (c-contiguous — the MFMA A-operand layout for conv0).
// ---------------------------------------------------------------------------
template<int F, bool WRITE_F32>
__global__ __launch_bounds__(256) void gathermax_kernel(const float* __restrict__ U,
                                                        const float* __restrict__ T,
                                                        const int* __restrict__ idx,
                                                        float* __restrict__ Y, int bsY,
                                                        unsigned short* __restrict__ HtH,
                                                        unsigned short* __restrict__ HtL,
                                                        int hoff) {
    const int N = NPTS, K = 20, FG = F / 8;
    __shared__ int sidx[32 * 20];
    const int b = blockIdx.y, n0 = blockIdx.x * 32, tid = threadIdx.x;
    const int p = tid >> 3, fg = tid & 7;
    for (int t = tid; t < 32 * K; t += 256) sidx[t] = idx[(b * N + n0) * K + t];
    __syncthreads();
    const int n = n0 + p;
    const float* __restrict__ Ub = U + (size_t)b * N * F;
    const int fbase = fg * FG;
    float mx[FG];
#pragma unroll
    for (int i = 0; i < FG; ++i) mx[i] = -__builtin_inff();
#pragma unroll 4
    for (int j = 0; j < K; ++j) {
        const int r = sidx[p * K + j];
        const float4* up = (const float4*)&Ub[(size_t)r * F + fbase];
#pragma unroll
        for (int q = 0; q < FG / 4; ++q) {
            float4 a = up[q];
            mx[q * 4 + 0] = fmaxf(mx[q * 4 + 0], a.x);
            mx[q * 4 + 1] = fmaxf(mx[q * 4 + 1], a.y);
            mx[q * 4 + 2] = fmaxf(mx[q * 4 + 2], a.z);
            mx[q * 4 + 3] = fmaxf(mx[q * 4 + 3], a.w);
        }
    }
    float val[FG];
#pragma unroll
    for (int i = 0; i < FG; ++i) {
        const int f = fbase + i;
        val[i] = T[((size_t)b * F + f) * N + n] + mx[i];
        if (WRITE_F32) Y[(size_t)b * bsY + (size_t)f * N + n] = val[i];
    }
    // bf16 hi/lo split, c-contiguous at Ht[b][n][hoff + fbase ...]
    unsigned short hs[FG], ls[FG];
#pragma unroll
    for (int i = 0; i < FG; ++i) {
        unsigned short h = f2bf(val[i]);
        hs[i] = h;
        ls[i] = f2bf(val[i] - bf2f(h));
    }
    const size_t hb = ((size_t)b * N + n) * 320 + hoff + fbase;
#pragma unroll
    for (int q = 0; q < FG / 8; ++q) {
        *(int4*)&HtH[hb + q * 8] = *(const int4*)&hs[q * 8];
        *(int4*)&HtL[hb + q * 8] = *(const int4*)&ls[q * 8];
    }
}

// ---------------------------------------------------------------------------
// conv0_w -> bf16 hi/lo split (one-shot, 1024x320 elements).
// ---------------------------------------------------------------------------
__global__ __launch_bounds__(256) void wsplit_kernel(const float* __restrict__ W,
                                                     unsigned short* __restrict__ WH,
                                                     unsigned short* __restrict__ WL) {
    const int e = blockIdx.x * 256 + threadIdx.x;
    float w = W[e];
    unsigned short h = f2bf(w);
    WH[e] = h;
    WL[e] = f2bf(w - bf2f(h));
}

// ---------------------------------------------------------------------------
// conv0 + global max via bf16x3 MFMA emulation:
//   W.H ~= Whi.Hhi + Whi.Hlo + Wlo.Hhi  (error ~2^-18 rel per term).
// Block tile: 64 n x 128 f; per wave 32n x 64f = 2x4 16x16x32 tiles, 3 MFMA
// each per 32-c chunk. LDS rows padded to 40 shorts: b128 frag reads spread
// uniformly over all 8 bank-quads (conflict-free).
// ---------------------------------------------------------------------------
__global__ __launch_bounds__(256) void conv0mfma_kernel(const unsigned short* __restrict__ HtH,
                                                        const unsigned short* __restrict__ HtL,
                                                        const unsigned short* __restrict__ WH,
                                                        const unsigned short* __restrict__ WL,
                                                        unsigned* __restrict__ M) {
    const int N = NPTS;
    __shared__ unsigned short HsH[64][40], HsL[64][40], WsH[128][40], WsL[128][40];
    const int n0 = blockIdx.x * 64, f0 = blockIdx.y * 128, b = blockIdx.z;
    const int tid = threadIdx.x;
    const int wave = tid >> 6, lane = tid & 63;
    const int wm = wave & 1, wf = wave >> 1;
    const int row = lane & 15, quad = lane >> 4;
    f32x4 acc[2][4];
#pragma unroll
    for (int i = 0; i < 2; ++i)
#pragma unroll
        for (int j = 0; j < 4; ++j) acc[i][j] = (f32x4){0.f, 0.f, 0.f, 0.f};

    const int hn = tid >> 2, hq = tid & 3;   // H staging: 64 rows x 4 chunks
    const int wfr = tid >> 1, wq = tid & 1;  // W staging: 128 rows x 2 chunks

    for (int c0 = 0; c0 < 320; c0 += 32) {
        {
            const size_t src = ((size_t)b * N + n0 + hn) * 320 + c0 + hq * 8;
            *(int4*)&HsH[hn][hq * 8] = *(const int4*)&HtH[src];
            *(int4*)&HsL[hn][hq * 8] = *(const int4*)&HtL[src];
        }
        {
            const size_t src = (size_t)(f0 + wfr) * 320 + c0 + wq * 16;
            *(int4*)&WsH[wfr][wq * 16]     = *(const int4*)&WH[src];
            *(int4*)&WsH[wfr][wq * 16 + 8] = *(const int4*)&WH[src + 8];
            *(int4*)&WsL[wfr][wq * 16]     = *(const int4*)&WL[src];
            *(int4*)&WsL[wfr][wq * 16 + 8] = *(const int4*)&WL[src + 8];
        }
        __syncthreads();
        bf16x8 aH[2], aL[2];
#pragma unroll
        for (int mt = 0; mt < 2; ++mt) {
            aH[mt] = *(const bf16x8*)&HsH[wm * 32 + mt * 16 + row][quad * 8];
            aL[mt] = *(const bf16x8*)&HsL[wm * 32 + mt * 16 + row][quad * 8];
        }
#pragma unroll
        for (int nt = 0; nt < 4; ++nt) {
            bf16x8 bH = *(const bf16x8*)&WsH[wf * 64 + nt * 16 + row][quad * 8];
            bf16x8 bL = *(const bf16x8*)&WsL[wf * 64 + nt * 16 + row][quad * 8];
#pragma unroll
            for (int mt = 0; mt < 2; ++mt) {
                acc[mt][nt] = __builtin_amdgcn_mfma_f32_16x16x32_bf16(aH[mt], bH, acc[mt][nt], 0, 0, 0);
                acc[mt][nt] = __builtin_amdgcn_mfma_f32_16x16x32_bf16(aH[mt], bL, acc[mt][nt], 0, 0, 0);
                acc[mt][nt] = __builtin_amdgcn_mfma_f32_16x16x32_bf16(aL[mt], bH, acc[mt][nt], 0, 0, 0);
            }
        }
        __syncthreads();
    }
    // D[m=n_pt][col=f]: col = lane&15, row = quad*4 + reg. Max over this
    // wave's 32 n: lane-local (2 mt x 4 regs), then across quads (shfl 16,32).
#pragma unroll
    for (int nt = 0; nt < 4; ++nt) {
        float m = acc[0][nt][0];
#pragma unroll
        for (int r = 1; r < 4; ++r) m = fmaxf(m, acc[0][nt][r]);
#pragma unroll
        for (int r = 0; r < 4; ++r) m = fmaxf(m, acc[1][nt][r]);
        m = fmaxf(m, __shfl_down(m, 16));
        m = fmaxf(m, __shfl_down(m, 32));
        if (quad == 0)
            atomicMax(&M[(b << 10) + f0 + wf * 64 + nt * 16 + row], fenc(m));
    }
}

// ---------------------------------------------------------------------------
// Fused head (unchanged).
// ---------------------------------------------------------------------------
__global__ __launch_bounds__(256) void fc_kernel(const unsigned* __restrict__ M,
    const float* __restrict__ cb, const float* __restrict__ cs, const float* __restrict__ ct,
    const float* __restrict__ w0, const float* __restrict__ b0, const float* __restrict__ s0, const float* __restrict__ t0,
    const float* __restrict__ w1, const float* __restrict__ b1, const float* __restrict__ s1, const float* __restrict__ t1,
    const float* __restrict__ w2, const float* __restrict__ b2, const float* __restrict__ s2, const float* __restrict__ t2,
    float* __restrict__ out) {
    __shared__ float g0[1024], g1[512], g2[256];
    const int b = blockIdx.x, tid = threadIdx.x;
    for (int f = tid; f < 1024; f += 256) {
        float z = fdec(M[b * 1024 + f]);
        float g = cs[f] * (z + cb[f]) + ct[f];
        g0[f] = fmaxf(g, 0.f);
    }
    __syncthreads();
    for (int f = tid; f < 512; f += 256) {
        const float4* wp = (const float4*)(w0 + (size_t)f * 1024);
        float acc = 0.f;
#pragma unroll 4
        for (int c = 0; c < 256; ++c) {
            float4 wv = wp[c];
            float4 gv = *(const float4*)&g0[c * 4];
            acc += wv.x * gv.x + wv.y * gv.y + wv.z * gv.z + wv.w * gv.w;
        }
        float g = s0[f] * (acc + b0[f]) + t0[f];
        g1[f] = fmaxf(g, 0.f);
    }
    __syncthreads();
    if (tid < 256) {
        const float4* wp = (const float4*)(w1 + (size_t)tid * 512);
        float acc = 0.f;
#pragma unroll 4
        for (int c = 0; c < 128; ++c) {
            float4 wv = wp[c];
            float4 gv = *(const float4*)&g1[c * 4];
            acc += wv.x * gv.x + wv.y * gv.y + wv.z * gv.z + wv.w * gv.w;
        }
        float g = s1[tid] * (acc + b1[tid]) + t1[tid];
        g2[tid] = fmaxf(g, 0.f);
    }
    __syncthreads();
    if (tid < 40) {
        const float4* wp = (const float4*)(w2 + (size_t)tid * 256);
        float acc = 0.f;
#pragma unroll 4
        for (int c = 0; c < 64; ++c) {
            float4 wv = wp[c];
            float4 gv = *(const float4*)&g2[c * 4];
            acc += wv.x * gv.x + wv.y * gv.y + wv.z * gv.z + wv.w * gv.w;
        }
        float g = s2[tid] * (acc + b2[tid]) + t2[tid];
        out[b * 40 + tid] = fmaxf(g, 0.f);
    }
}

// ---------------------------------------------------------------------------
extern "C" void kernel_launch(void* const* d_in, const int* in_sizes, int n_in,
                              void* d_out, int out_size, void* d_ws, size_t ws_size,
                              hipStream_t stream) {
    const float* x       = (const float*)d_in[0];
    const float* ec0_w   = (const float*)d_in[1];
    const float* ec0_b   = (const float*)d_in[2];
    const float* ec1_w   = (const float*)d_in[3];
    const float* ec1_b   = (const float*)d_in[4];
    const float* ec2_w   = (const float*)d_in[5];
    const float* ec2_b   = (const float*)d_in[6];
    const float* ec3_w   = (const float*)d_in[7];
    const float* ec3_b   = (const float*)d_in[8];
    const float* conv0_w = (const float*)d_in[9];
    const float* conv0_b = (const float*)d_in[10];
    const float* conv0_s = (const float*)d_in[11];
    const float* conv0_t = (const float*)d_in[12];
    const float* fc0_w   = (const float*)d_in[13];
    const float* fc0_b   = (const float*)d_in[14];
    const float* fc0_s   = (const float*)d_in[15];
    const float* fc0_t   = (const float*)d_in[16];
    const float* fc1_w   = (const float*)d_in[17];
    const float* fc1_b   = (const float*)d_in[18];
    const float* fc1_s   = (const float*)d_in[19];
    const float* fc1_t   = (const float*)d_in[20];
    const float* fc2_w   = (const float*)d_in[21];
    const float* fc2_b   = (const float*)d_in[22];
    const float* fc2_s   = (const float*)d_in[23];
    const float* fc2_t   = (const float*)d_in[24];
    float* out = (float*)d_out;

    char* ws = (char*)d_ws;
    const int B = 16, N = NPTS;
    float* Hc   = (float*)(ws + 0);            // [16][320][2048]  41,943,040 B
    float* U    = (float*)(ws + 41943040);     // [16][2048][128]  16,777,216 B
    float* T    = (float*)(ws + 58720256);     // [16][128][2048]  16,777,216 B
    int*   I    = (int*)  (ws + 75497472);     // [16][2048][20]    2,621,440 B
    unsigned* M = (unsigned*)(ws + 78118912);  // [16][1024]           65,536 B
    unsigned short* W_hi = (unsigned short*)(ws + 78184448);  //  655,360 B
    unsigned short* W_lo = (unsigned short*)(ws + 78839808);  //  655,360 B
    unsigned short* HtH  = (unsigned short*)(ws + 79495168);  // [16][2048][320] 20,971,520 B
    unsigned short* HtL  = (unsigned short*)(ws + 100466688); // [16][2048][320] 20,971,520 B
    // end: 121,438,208 B

    (void)hipFuncSetAttribute((const void*)knnfused_kernel,
                              hipFuncAttributeMaxDynamicSharedMemorySize, 69632);

    dim3 blk(256);
    const int bsX0 = 3 * N, bsH = 320 * N;

    wsplit_kernel<<<dim3(1024 * 320 / 256), blk, 0, stream>>>(conv0_w, W_hi, W_lo);

    // ---- Layer 0 (C=3 -> F=64) ----
    select0_kernel<<<dim3(B * N / 4), blk, 0, stream>>>(x, I);
    ut_kernel<64, 3><<<dim3(N / 64, 1, B), blk, 0, stream>>>(x, bsX0, ec0_w, ec0_b, U, T);
    gathermax_kernel<64, true><<<dim3(N / 32, B), blk, 0, stream>>>(U, T, I, Hc, bsH, HtH, HtL, 0);

    // ---- Layers 1..3 (C=64): fused dist+select with inline sq ----
    const float* Xin[3] = {Hc, Hc + (size_t)64 * N, Hc + (size_t)128 * N};
    const float* ecw[3] = {ec1_w, ec2_w, ec3_w};
    const float* ecb[3] = {ec1_b, ec2_b, ec3_b};
    for (int L = 0; L < 3; ++L) {
        knnfused_kernel<<<dim3(N / 8, B), blk, 69632, stream>>>(Xin[L], bsH, I);
        if (L < 2) {
            ut_kernel<64, 64><<<dim3(N / 64, 1, B), blk, 0, stream>>>(Xin[L], bsH, ecw[L], ecb[L], U, T);
            gathermax_kernel<64, true><<<dim3(N / 32, B), blk, 0, stream>>>(
                U, T, I, Hc + (size_t)(64 * (L + 1)) * N, bsH, HtH, HtL, 64 * (L + 1));
        } else {
            ut_kernel<128, 64><<<dim3(N / 64, 2, B), blk, 0, stream>>>(Xin[L], bsH, ecw[L], ecb[L], U, T);
            gathermax_kernel<128, false><<<dim3(N / 32, B), blk, 0, stream>>>(
                U, T, I, Hc + (size_t)192 * N, bsH, HtH, HtL, 192);
        }
    }

    // ---- conv0 + global max (bf16x3 MFMA) ----
    (void)hipMemsetAsync(M, 0, B * 1024 * sizeof(unsigned), stream);
    conv0mfma_kernel<<<dim3(N / 64, 1024 / 128, B), blk, 0, stream>>>(HtH, HtL, W_hi, W_lo, M);

    // ---- head ----
    fc_kernel<<<dim3(B), blk, 0, stream>>>(M, conv0_b, conv0_s, conv0_t,
                                           fc0_w, fc0_b, fc0_s, fc0_t,
                                           fc1_w, fc1_b, fc1_s, fc1_t,
                                           fc2_w, fc2_b, fc2_s, fc2_t, out);
}